// Round 2
// baseline (438.646 us; speedup 1.0000x reference)
//
#include <hip/hip_runtime.h>
#include <cstdint>
#include <cstddef>

// ---------------------------------------------------------------------------
// EfficientAttention, Q-folded pipeline (Round 4, resubmit after broker
// timeout):
//   out = x @ (Wq @ Wfused[b]) + bias
// Stages:
//   K0a  cast x fp32->bf16                        (Xb)
//   K0b  tiled transpose+cast Wqkv -> WqkvT, Wproj -> WpT; cast Wq
//   K1   GEMM1 (phase-interleaved, ring-3 LDS, counted vmcnt): kv = Xb@Wqkv[:,768:]
//          epilogue scatters k -> KT[96][64][4096], v -> VT[96][64][4096]
//   K3   stats: per KT row (bh,d): m = max_n, inv = 1/sum exp(k-m)
//   K4   ctx partials: exp applied inline; KT,VT -> part fp32
//   K5   wfused: B2T[b][c'][h*64+d] = sum_e ctx[d,e]*Wproj[h*64+e,c']
//   K5b  combine: Wcomb^T[b] = B2T[b] @ Wq^T
//   K6   GEMM2 (same template as K1): out[b] = Xb[b] @ Wcomb[b]^T + bproj
// ---------------------------------------------------------------------------

typedef __bf16 bf8_t __attribute__((ext_vector_type(8)));
typedef float f4_t __attribute__((ext_vector_type(4)));

#define DEV_INLINE __device__ __forceinline__

DEV_INLINE void gload16(const void* g, void* l) {
  __builtin_amdgcn_global_load_lds(
      (const __attribute__((address_space(1))) void*)g,
      (__attribute__((address_space(3))) void*)l, 16, 0, 0);
}

// ---------------- K0a: cast x (fp32) -> bf16, 4 elems/thread ----------------
__global__ __launch_bounds__(256) void cast_f32_bf16(const float* __restrict__ in,
                                                     __bf16* __restrict__ out, int n4) {
  int i = blockIdx.x * 256 + threadIdx.x;
  if (i >= n4) return;
  float4 f = ((const float4*)in)[i];
  union { __bf16 h[4]; uint2 u; } o;
  o.h[0] = (__bf16)f.x; o.h[1] = (__bf16)f.y; o.h[2] = (__bf16)f.z; o.h[3] = (__bf16)f.w;
  ((uint2*)out)[i] = o.u;
}

// ---------- K0b: tiled transpose: out[c*R + r] = (bf16) in[r*C + c] ---------
__global__ __launch_bounds__(256) void transpose_cast(const float* __restrict__ in,
                                                      __bf16* __restrict__ out, int R, int C) {
  __shared__ float t[64][65];
  const int tilesR = R >> 6;
  const int tr = blockIdx.x % tilesR, tc = blockIdx.x / tilesR;
  const int tx = threadIdx.x & 63, ty = threadIdx.x >> 6;
  const int r0 = tr * 64, c0 = tc * 64;
#pragma unroll
  for (int p = 0; p < 16; p++) {
    int r = p * 4 + ty;
    t[r][tx] = in[(size_t)(r0 + r) * C + c0 + tx];
  }
  __syncthreads();
#pragma unroll
  for (int p = 0; p < 16; p++) {
    int c = p * 4 + ty;
    out[(size_t)(c0 + c) * R + r0 + tx] = (__bf16)t[tx][c];
  }
}

// ---- K0c: Wq_cast[r][k] = (bf16) Wqkv[r][k], k<768 (strided row cast) ------
__global__ __launch_bounds__(256) void wq_cast(const float* __restrict__ in,
                                               __bf16* __restrict__ out) {
  int o = blockIdx.x * 256 + threadIdx.x;   // o in [0, 768*768)
  int r = o / 768, c = o - r * 768;
  out[o] = (__bf16)in[r * 2304 + c];
}

// ---------------------------------------------------------------------------
// Shared phase-interleaved GEMM template (BM=256, BN=128, BK=64, 512 thr).
//   - 3-deep LDS K-tile ring: iter t computes ring[t%3], stages t+2 into
//     ring[(t+2)%3] (written buffer is never concurrently read -> race-free).
//   - counted s_waitcnt vmcnt(6) once per K-tile (tile t+2's 6 units stay in
//     flight; guarantees tile t+1 fully landed before next iteration).
//   - 8-slot XOR swizzle: LDS slot s holds global 16B-chunk (s ^ (row&7)),
//     achieved by pre-swizzling the per-lane GLOBAL source address
//     (global_load_lds writes linearly: base + lane*16).  ds_read_b128 of a
//     column slice then hits every bank exactly 8x (the b128 minimum).
//   - 4 quadrant phases per K-tile: 8 ds_read_b128 + 8 MFMA 16x16x32 each,
//     barrier-paired, setprio(1) around the MFMA cluster (T5).
// Per-wave output 64x64: acc[ri][ci] (16x16 frags), waves 4M x 2N.
// ---------------------------------------------------------------------------

#define SA_(buf, u, kc) gload16(gA + (size_t)((u) * 64) * 768 + (kc), dAl + (buf) * 16384 + (u) * 4096)
#define SB_(buf, u, kc) gload16(gB + (size_t)((u) * 64) * 768 + (kc), dBl + (buf) * 8192 + (u) * 4096)

#define PH_(q, STAGE, TAIL) do {                                              \
    bf8_t af[2][2], bfr[2][2];                                                \
    _Pragma("unroll") for (int i_ = 0; i_ < 2; i_++)                          \
      _Pragma("unroll") for (int ks_ = 0; ks_ < 2; ks_++) {                   \
        af[i_][ks_]  = *(const bf8_t*)(aB + offA[2 * ((q) >> 1) + i_][ks_]);  \
        bfr[i_][ks_] = *(const bf8_t*)(bB + offB[2 * ((q) & 1) + i_][ks_]);   \
      }                                                                       \
    STAGE;                                                                    \
    __builtin_amdgcn_s_barrier();                                             \
    __builtin_amdgcn_s_setprio(1);                                            \
    _Pragma("unroll") for (int ks_ = 0; ks_ < 2; ks_++)                       \
      _Pragma("unroll") for (int i_ = 0; i_ < 2; i_++)                        \
        _Pragma("unroll") for (int j_ = 0; j_ < 2; j_++)                      \
          acc[2 * ((q) >> 1) + i_][2 * ((q) & 1) + j_] =                      \
            __builtin_amdgcn_mfma_f32_16x16x32_bf16(af[i_][ks_], bfr[j_][ks_],\
              acc[2 * ((q) >> 1) + i_][2 * ((q) & 1) + j_], 0, 0, 0);         \
    __builtin_amdgcn_s_setprio(0);                                            \
    TAIL;                                                                     \
    __builtin_amdgcn_s_barrier();                                             \
  } while (0)

// K = 768 = 12 tiles of BK=64.  Main loop t=0..9 (stages t+2, vmcnt(6));
// tail t=10 (no stage, vmcnt(0) ensures t=11 landed); tail t=11 (pure).
#define MAIN_LOOP() do {                                                      \
    SA_(0, 0, 0); SA_(0, 1, 0); SA_(0, 2, 0); SA_(0, 3, 0);                   \
    SB_(0, 0, 0); SB_(0, 1, 0);                                               \
    SA_(1, 0, 64); SA_(1, 1, 64); SA_(1, 2, 64); SA_(1, 3, 64);               \
    SB_(1, 0, 64); SB_(1, 1, 64);                                             \
    asm volatile("s_waitcnt vmcnt(6)" ::: "memory");                          \
    __builtin_amdgcn_s_barrier();                                             \
    int cur = 0;                                                              \
    for (int t = 0; t < 10; t++) {                                            \
      const __bf16* aB = sA + cur * 16384;                                    \
      const __bf16* bB = sB + cur * 8192;                                     \
      int nx = cur + 2; if (nx > 2) nx -= 3;                                  \
      const int kc = (t + 2) * 64;                                            \
      PH_(0, { SA_(nx, 0, kc); SA_(nx, 1, kc); }, {});                        \
      PH_(1, { SA_(nx, 2, kc); SA_(nx, 3, kc); }, {});                        \
      PH_(2, { SB_(nx, 0, kc); }, {});                                        \
      PH_(3, { SB_(nx, 1, kc); },                                             \
          { asm volatile("s_waitcnt vmcnt(6)" ::: "memory"); });              \
      cur++; if (cur > 2) cur = 0;                                            \
    }                                                                         \
    { const __bf16* aB = sA + cur * 16384;                                    \
      const __bf16* bB = sB + cur * 8192;                                     \
      PH_(0, {}, {}); PH_(1, {}, {}); PH_(2, {}, {});                         \
      PH_(3, {}, { asm volatile("s_waitcnt vmcnt(0)" ::: "memory"); });       \
      cur++; if (cur > 2) cur = 0; }                                          \
    { const __bf16* aB = sA + cur * 16384;                                    \
      const __bf16* bB = sB + cur * 8192;                                     \
      PH_(0, {}, {}); PH_(1, {}, {}); PH_(2, {}, {}); PH_(3, {}, {}); }       \
  } while (0)

#define GEMM_SETUP()                                                          \
  const int tid = threadIdx.x;                                                \
  const int trow = tid >> 3;                                                  \
  const int gcol = ((tid & 7) ^ (trow & 7)) * 8;                              \
  __bf16* dAl = sA + tid * 8;                                                 \
  __bf16* dBl = sB + tid * 8;                                                 \
  const int lane = tid & 63, wv = tid >> 6;                                   \
  const int wm = wv >> 1, wn = wv & 1;                                        \
  const int lr = lane & 15, quad = lane >> 4, rsw = lr & 7;                   \
  int offA[4][2], offB[4][2];                                                 \
  _Pragma("unroll") for (int f_ = 0; f_ < 4; f_++)                            \
    _Pragma("unroll") for (int ks_ = 0; ks_ < 2; ks_++) {                     \
      offA[f_][ks_] = (wm * 64 + f_ * 16 + lr) * 64 + (((ks_ * 4 + quad) ^ rsw) * 8); \
      offB[f_][ks_] = (wn * 64 + f_ * 16 + lr) * 64 + (((ks_ * 4 + quad) ^ rsw) * 8); \
    }                                                                         \
  f4_t acc[4][4];                                                             \
  _Pragma("unroll") for (int i_ = 0; i_ < 4; i_++)                            \
    _Pragma("unroll") for (int j_ = 0; j_ < 4; j_++)                          \
      acc[i_][j_] = (f4_t){0.f, 0.f, 0.f, 0.f};

// ---------------- K1: GEMM1 kv = Xb @ Wqkv[:,768:] --------------------------
// A [32768,768] bf16 RM, B^T = WqkvT rows 768..2303 [1536,768] bf16 RM.
// grid 1536 = 128 mt x 12 nt; XCD swizzle: 16 mts per XCD (A-tile L2 reuse).
__global__ __launch_bounds__(512, 2) void gemm1_kv(const __bf16* __restrict__ A,
                                                   const __bf16* __restrict__ B,
                                                   __bf16* __restrict__ KTo,
                                                   __bf16* __restrict__ VTo) {
  __shared__ __bf16 sA[3 * 16384];   // 3 x [256][64], 96 KiB
  __shared__ __bf16 sB[3 * 8192];    // 3 x [128][64], 48 KiB
  const int xcd = blockIdx.x & 7, g = blockIdx.x >> 3;
  const int mt = xcd * 16 + g / 12, nt = g % 12;
  GEMM_SETUP();
  const __bf16* gA = A + (size_t)(mt * 256 + trow) * 768 + gcol;
  const __bf16* gB = B + (size_t)(nt * 128 + trow) * 768 + gcol;

  MAIN_LOOP();

  // epilogue: C row = n-dim, col in [0,1536): nt<6 -> K, nt>=6 -> V.
  // C/D frag layout: col = lane&15, row = quad*4 + reg.
  const int s = nt / 6;
  __bf16* T = s ? VTo : KTo;
  const int colbase = (nt % 6) * 128 + wn * 64;
  const int bidx = mt >> 4;                       // 256-row tile never crosses batch
  const int nbase = (mt & 15) * 256 + wm * 64 + quad * 4;
#pragma unroll
  for (int ci = 0; ci < 4; ci++) {
    int col = colbase + ci * 16 + lr;
    int h = col >> 6, d = col & 63;
    __bf16* Tp = T + ((size_t)(bidx * 12 + h) * 64 + d) * 4096;
#pragma unroll
    for (int ri = 0; ri < 4; ri++) {
      union { __bf16 h4[4]; uint2 u2; } pk;
#pragma unroll
      for (int r = 0; r < 4; r++) pk.h4[r] = (__bf16)acc[ri][ci][r];
      *(uint2*)&Tp[nbase + ri * 16] = pk.u2;
    }
  }
}

// ------ K3: row stats (max, 1/sumexp) per KT row; NO writeback --------------
__global__ __launch_bounds__(256) void stats_rows(const __bf16* __restrict__ KT,
                                                  float2* __restrict__ stats) {
  __shared__ float red[8];
  const __bf16* p = KT + (size_t)blockIdx.x * 4096;
  const int tid = threadIdx.x, lane = tid & 63, wv = tid >> 6;
  bf8_t x0 = *(const bf8_t*)&p[tid * 16];
  bf8_t x1 = *(const bf8_t*)&p[tid * 16 + 8];
  float v[16];
#pragma unroll
  for (int k = 0; k < 8; k++) { v[k] = (float)x0[k]; v[8 + k] = (float)x1[k]; }
  float m = v[0];
#pragma unroll
  for (int k = 1; k < 16; k++) m = fmaxf(m, v[k]);
  for (int o = 32; o; o >>= 1) m = fmaxf(m, __shfl_xor(m, o, 64));
  if (lane == 0) red[wv] = m;
  __syncthreads();
  m = fmaxf(fmaxf(red[0], red[1]), fmaxf(red[2], red[3]));
  float s = 0.f;
#pragma unroll
  for (int k = 0; k < 16; k++) s += __expf(v[k] - m);
  for (int o = 32; o; o >>= 1) s += __shfl_xor(s, o, 64);
  if (lane == 0) red[4 + wv] = s;
  __syncthreads();
  if (tid == 0) {
    float st = red[4] + red[5] + red[6] + red[7];
    stats[blockIdx.x] = make_float2(m, 1.0f / st);
  }
}

// --------- K4: ctx partials with inline exp. grid = 96*8 --------------------
__global__ __launch_bounds__(256) void ctx_kernel(const __bf16* __restrict__ KT,
                                                  const __bf16* __restrict__ VT,
                                                  const float2* __restrict__ stats,
                                                  float* __restrict__ part) {
  const int bh = blockIdx.x >> 3, kc = blockIdx.x & 7;
  const int tid = threadIdx.x, lane = tid & 63, wv = tid >> 6;
  const int wr = (wv >> 1) * 32, wc = (wv & 1) * 32;
  const int lr = lane & 15, quad = lane >> 4;
  const __bf16* Ab = KT + (size_t)bh * 64 * 4096;
  const __bf16* Bb = VT + (size_t)bh * 64 * 4096;
  float2 st[2];
  st[0] = stats[bh * 64 + wr + lr];
  st[1] = stats[bh * 64 + wr + 16 + lr];
  const f4_t fz = {0.f, 0.f, 0.f, 0.f};
  f4_t acc[2][2] = {{fz, fz}, {fz, fz}};
  const int kbeg = kc * 512;
  for (int k0 = kbeg; k0 < kbeg + 512; k0 += 32) {
    bf8_t a[2], b[2];
#pragma unroll
    for (int i = 0; i < 2; i++) {
      bf8_t raw = *(const bf8_t*)&Ab[(size_t)(wr + i * 16 + lr) * 4096 + k0 + quad * 8];
#pragma unroll
      for (int e = 0; e < 8; e++)
        a[i][e] = (__bf16)(__expf((float)raw[e] - st[i].x) * st[i].y);
    }
#pragma unroll
    for (int j = 0; j < 2; j++)
      b[j] = *(const bf8_t*)&Bb[(size_t)(wc + j * 16 + lr) * 4096 + k0 + quad * 8];
#pragma unroll
    for (int i = 0; i < 2; i++)
#pragma unroll
      for (int j = 0; j < 2; j++)
        acc[i][j] = __builtin_amdgcn_mfma_f32_16x16x32_bf16(a[i], b[j], acc[i][j], 0, 0, 0);
  }
  float* po = part + (size_t)blockIdx.x * 4096;
#pragma unroll
  for (int i = 0; i < 2; i++)
#pragma unroll
    for (int j = 0; j < 2; j++)
#pragma unroll
      for (int r = 0; r < 4; r++)
        po[(wr + i * 16 + quad * 4 + r) * 64 + wc + j * 16 + lr] = acc[i][j][r];
}

// -------- K5: B2T[b][c][h*64+d] = sum_e ctx[bh][d][e] * Wproj[h*64+e][c] ----
__global__ __launch_bounds__(256) void wfused_kernel(const float* __restrict__ part,
                                                     const __bf16* __restrict__ WpT,
                                                     __bf16* __restrict__ B2T) {
  __shared__ __bf16 sctx[64 * 64];
  const int bh = blockIdx.x, cblk = blockIdx.y;
  const int b = bh / 12, h = bh % 12;
  const int tid = threadIdx.x;
  for (int i = tid; i < 4096; i += 256) {
    float s = 0.f;
#pragma unroll
    for (int kc = 0; kc < 8; kc++) s += part[(size_t)(bh * 8 + kc) * 4096 + i];
    sctx[i] = (__bf16)s;
  }
  __syncthreads();
  const int lane = tid & 63, wv = tid >> 6, lr = lane & 15, quad = lane >> 4;
  const int c0 = cblk * 192 + wv * 48;
  const f4_t fz = {0.f, 0.f, 0.f, 0.f};
  f4_t acc[3][4];
#pragma unroll
  for (int i = 0; i < 3; i++)
#pragma unroll
    for (int j = 0; j < 4; j++) acc[i][j] = fz;
#pragma unroll
  for (int k0 = 0; k0 < 64; k0 += 32) {
    bf8_t a[3], bq[4];
#pragma unroll
    for (int i = 0; i < 3; i++)
      a[i] = *(const bf8_t*)&WpT[(size_t)(c0 + i * 16 + lr) * 768 + h * 64 + k0 + quad * 8];
#pragma unroll
    for (int j = 0; j < 4; j++)
      bq[j] = *(const bf8_t*)&sctx[(j * 16 + lr) * 64 + k0 + quad * 8];
#pragma unroll
    for (int i = 0; i < 3; i++)
#pragma unroll
      for (int j = 0; j < 4; j++)
        acc[i][j] = __builtin_amdgcn_mfma_f32_16x16x32_bf16(a[i], bq[j], acc[i][j], 0, 0, 0);
  }
#pragma unroll
  for (int i = 0; i < 3; i++)
#pragma unroll
    for (int j = 0; j < 4; j++)
#pragma unroll
      for (int r = 0; r < 4; r++) {
        int c = c0 + i * 16 + quad * 4 + r;
        int d = j * 16 + lr;
        B2T[((size_t)b * 768 + c) * 768 + h * 64 + d] = (__bf16)acc[i][j][r];
      }
}

// ------ K5b: combine  Wcomb^T[b][c_out][c_in] = sum_k B2T[b][c_out][k]*Wq[c_in][k]
__global__ __launch_bounds__(256) void combine_kernel(const __bf16* __restrict__ B2Tall,
                                                      const __bf16* __restrict__ Wq,
                                                      __bf16* __restrict__ Wcomb) {
  constexpr int LD = 768, BK = 32, KTOT = 768;
  __shared__ __bf16 sAc[64 * 32];
  __shared__ __bf16 sBc[64 * 32];
  const int b = blockIdx.x / 144, rem = blockIdx.x % 144;
  const int mt = rem / 12, nt = rem % 12;
  const __bf16* A = B2Tall + (size_t)b * 768 * 768;
  const int tid = threadIdx.x, lane = tid & 63, wv = tid >> 6;
  const int wr = (wv >> 1) * 32, wc = (wv & 1) * 32;
  const int lr = lane & 15, quad = lane >> 4;

  const int e0 = tid * 8;
  const int srow = e0 >> 5, skk = e0 & 31;
  const __bf16* gA = A + (size_t)(mt * 64 + srow) * LD + skk;
  const __bf16* gB = Wq + (size_t)(nt * 64 + srow) * LD + skk;

  const f4_t fz = {0.f, 0.f, 0.f, 0.f};
  f4_t acc[2][2] = {{fz, fz}, {fz, fz}};

  for (int k0 = 0; k0 < KTOT; k0 += BK) {
    gload16(gA, &sAc[e0]);
    gload16(gB, &sBc[e0]);
    gA += BK; gB += BK;
    __syncthreads();
    bf8_t a[2], bq[2];
#pragma unroll
    for (int i = 0; i < 2; i++)
      a[i] = *(const bf8_t*)&sAc[(wr + i * 16 + lr) * 32 + quad * 8];
#pragma unroll
    for (int j = 0; j < 2; j++)
      bq[j] = *(const bf8_t*)&sBc[(wc + j * 16 + lr) * 32 + quad * 8];
#pragma unroll
    for (int i = 0; i < 2; i++)
#pragma unroll
      for (int j = 0; j < 2; j++)
        acc[i][j] = __builtin_amdgcn_mfma_f32_16x16x32_bf16(a[i], bq[j], acc[i][j], 0, 0, 0);
    __syncthreads();
  }
  __bf16* C = Wcomb + (size_t)b * 768 * 768;
  const int row0 = mt * 64 + wr, col0 = nt * 64 + wc;
#pragma unroll
  for (int i = 0; i < 2; i++)
#pragma unroll
    for (int j = 0; j < 2; j++)
#pragma unroll
      for (int r = 0; r < 4; r++)
        C[(size_t)(row0 + i * 16 + quad * 4 + r) * 768 + col0 + j * 16 + lr] =
            (__bf16)acc[i][j][r];
}

// ------------- K6: GEMM2 out = Xb @ Wcomb^T[b] + bproj ----------------------
// grid 768 = 128 mt x 6 nt; XCD swizzle: each XCD owns one batch -> Wcomb
// (1.2 MB) L2-resident.
__global__ __launch_bounds__(512, 2) void gemm2_out(const __bf16* __restrict__ A,
                                                    const __bf16* __restrict__ Ball,
                                                    float* __restrict__ C,
                                                    const float* __restrict__ bias) {
  __shared__ __bf16 sA[3 * 16384];
  __shared__ __bf16 sB[3 * 8192];
  const int xcd = blockIdx.x & 7, g = blockIdx.x >> 3;
  const int mt = xcd * 16 + g / 6, nt = g % 6;
  const __bf16* B = Ball + (size_t)(mt >> 4) * 768 * 768;
  GEMM_SETUP();
  const __bf16* gA = A + (size_t)(mt * 256 + trow) * 768 + gcol;
  const __bf16* gB = B + (size_t)(nt * 128 + trow) * 768 + gcol;

  MAIN_LOOP();

  const int row0 = mt * 256 + wm * 64 + quad * 4;
  const int col0 = nt * 128 + wn * 64;
#pragma unroll
  for (int ci = 0; ci < 4; ci++) {
    int col = col0 + ci * 16 + lr;
    float bv = bias[col];
#pragma unroll
    for (int ri = 0; ri < 4; ri++) {
#pragma unroll
      for (int r = 0; r < 4; r++)
        C[(size_t)(row0 + ri * 16 + r) * 768 + col] = acc[ri][ci][r] + bv;
    }
  }
}

// ---------------------------------------------------------------------------
extern "C" void kernel_launch(void* const* d_in, const int* in_sizes, int n_in,
                              void* d_out, int out_size, void* d_ws, size_t ws_size,
                              hipStream_t stream) {
  const float* x = (const float*)d_in[0];      // [8,4096,768]
  const float* Wqkv = (const float*)d_in[1];   // [768,2304]
  const float* Wproj = (const float*)d_in[2];  // [768,768]
  const float* bproj = (const float*)d_in[3];  // [768]
  float* out = (float*)d_out;                  // [8,4096,768]

  char* ws = (char*)d_ws;
  __bf16* Xb    = (__bf16*)(ws + 0);            // 50,331,648
  __bf16* KT    = (__bf16*)(ws + 50331648);     // 50,331,648
  __bf16* VT    = (__bf16*)(ws + 100663296);    // 50,331,648
  __bf16* WqkvT = (__bf16*)(ws + 150994944);    //  3,538,944 (dead after gemm1)
  float2* stats = (float2*)(ws + 150994944);    //  49,152 (aliases dead WqkvT)
  __bf16* Wqc   = (__bf16*)(ws + 154533888);    //  1,179,648
  __bf16* WpT   = (__bf16*)(ws + 155713536);    //  1,179,648
  float*  part  = (float*)(ws + 156893184);     // 12,582,912
  __bf16* B2T   = (__bf16*)(ws + 169476096);    //  9,437,184
  __bf16* Wcomb = (__bf16*)(ws + 178913280);    //  9,437,184 -> end 188,350,464

  cast_f32_bf16<<<24576, 256, 0, stream>>>(x, Xb, 25165824 / 4);
  transpose_cast<<<12 * 36, 256, 0, stream>>>(Wqkv, WqkvT, 768, 2304);
  wq_cast<<<(768 * 768) / 256, 256, 0, stream>>>(Wqkv, Wqc);
  transpose_cast<<<12 * 12, 256, 0, stream>>>(Wproj, WpT, 768, 768);
  gemm1_kv<<<1536, 512, 0, stream>>>(Xb, WqkvT + 768 * 768, KT, VT);
  stats_rows<<<6144, 256, 0, stream>>>(KT, stats);
  ctx_kernel<<<96 * 8, 256, 0, stream>>>(KT, VT, stats, part);
  wfused_kernel<<<dim3(96, 4), 256, 0, stream>>>(part, WpT, B2T);
  combine_kernel<<<1152, 256, 0, stream>>>(B2T, Wqc, Wcomb);
  gemm2_out<<<768, 512, 0, stream>>>(Xb, Wcomb, out, bproj);
}

// Round 4
// 428.544 us; speedup vs baseline: 1.0236x; 1.0236x over previous
//
#include <hip/hip_runtime.h>
#include <cstdint>
#include <cstddef>

// ---------------------------------------------------------------------------
// EfficientAttention, Q-folded pipeline (Round 5, resubmit after broker
// timeout):
//   out = x @ (Wq @ Wfused[b]) + bias
// GEMM template rework vs R4: BM=256 BN=256 BK=32, 8 waves (2Mx4N), per-wave
// output 128x64 (8x4 frags) -> 12 ds_read_b128 per 64 MFMA per K-tile (each
// fragment read once; R4 re-read everything 2x at a 0.5 reads/MFMA ratio and
// was LDS-bound, MfmaUtil 22%).  Keeps: ring-3 LDS (96 KiB), counted
// vmcnt(4) at tile boundary only, pre-swizzled-global XOR (0 conflicts
// measured), 2 barriers per 16-MFMA phase, setprio around MFMA cluster.
// ---------------------------------------------------------------------------

typedef __bf16 bf8_t __attribute__((ext_vector_type(8)));
typedef float f4_t __attribute__((ext_vector_type(4)));

#define DEV_INLINE __device__ __forceinline__

DEV_INLINE void gload16(const void* g, void* l) {
  __builtin_amdgcn_global_load_lds(
      (const __attribute__((address_space(1))) void*)g,
      (__attribute__((address_space(3))) void*)l, 16, 0, 0);
}

// ---------------- K0a: cast x (fp32) -> bf16, 4 elems/thread ----------------
__global__ __launch_bounds__(256) void cast_f32_bf16(const float* __restrict__ in,
                                                     __bf16* __restrict__ out, int n4) {
  int i = blockIdx.x * 256 + threadIdx.x;
  if (i >= n4) return;
  float4 f = ((const float4*)in)[i];
  union { __bf16 h[4]; uint2 u; } o;
  o.h[0] = (__bf16)f.x; o.h[1] = (__bf16)f.y; o.h[2] = (__bf16)f.z; o.h[3] = (__bf16)f.w;
  ((uint2*)out)[i] = o.u;
}

// ---------- K0b: tiled transpose: out[c*R + r] = (bf16) in[r*C + c] ---------
__global__ __launch_bounds__(256) void transpose_cast(const float* __restrict__ in,
                                                      __bf16* __restrict__ out, int R, int C) {
  __shared__ float t[64][65];
  const int tilesR = R >> 6;
  const int tr = blockIdx.x % tilesR, tc = blockIdx.x / tilesR;
  const int tx = threadIdx.x & 63, ty = threadIdx.x >> 6;
  const int r0 = tr * 64, c0 = tc * 64;
#pragma unroll
  for (int p = 0; p < 16; p++) {
    int r = p * 4 + ty;
    t[r][tx] = in[(size_t)(r0 + r) * C + c0 + tx];
  }
  __syncthreads();
#pragma unroll
  for (int p = 0; p < 16; p++) {
    int c = p * 4 + ty;
    out[(size_t)(c0 + c) * R + r0 + tx] = (__bf16)t[tx][c];
  }
}

// ---- K0c: Wq_cast[r][k] = (bf16) Wqkv[r][k], k<768 (strided row cast) ------
__global__ __launch_bounds__(256) void wq_cast(const float* __restrict__ in,
                                               __bf16* __restrict__ out) {
  int o = blockIdx.x * 256 + threadIdx.x;   // o in [0, 768*768)
  int r = o / 768, c = o - r * 768;
  out[o] = (__bf16)in[r * 2304 + c];
}

// ---------------------------------------------------------------------------
// GEMM template: BM=256, BN=256, BK=32, 512 thr (8 waves 2Mx4N).
//   LDS ring-3: sA/sB each 3 x [256][32] bf16 (48 KiB each, 96 total).
//   Staging: 4 gload16/thread/K-tile (A rows 0-127,128-255; B same).
//     thread t -> row t>>2, LDS slot t&3; global chunk = (t&3)^(row&3)
//     (pre-swizzled source; LDS dest linear -> read-side XOR undoes it).
//   K-tile iteration = 2 phases x {reads, 2 gloads, bar, 16 MFMA, bar}:
//     phase A: read a[0..3] + b[0..3] (8 reads), MFMA acc[0..3][0..3]
//     phase B: read a[4..7] (4 reads, b held in regs), MFMA acc[4..7][0..3]
//   vmcnt(4) at K-tile boundary only (tile t+2's 4 loads stay in flight;
//   proves tile t+1 landed).  Ring-3 => staged buffer never concurrently read.
// ---------------------------------------------------------------------------

#define MFMA16(aa, bb, cc) cc = __builtin_amdgcn_mfma_f32_16x16x32_bf16(aa, bb, cc, 0, 0, 0)

#define SAu(buf, u, kc) gload16(gA + (size_t)((u) * 128) * 768 + (kc),        \
                                sA + (buf) * 8192 + (u) * 4096 + tid * 8)
#define SBu(buf, u, kc) gload16(gB + (size_t)((u) * 128) * 768 + (kc),        \
                                sB + (buf) * 8192 + (u) * 4096 + tid * 8)
#define STAGE_T(buf, kc) do { SAu(buf,0,kc); SAu(buf,1,kc); SBu(buf,0,kc); SBu(buf,1,kc); } while (0)

#define G_SETUP()                                                             \
  const int tid = threadIdx.x;                                                \
  const int srow = tid >> 2;                                                  \
  const int gcol = ((tid & 3) ^ (srow & 3)) * 8;                              \
  const int lane = tid & 63, wv = tid >> 6;                                   \
  const int wm = wv >> 2, wn = wv & 3;                                        \
  const int lr = lane & 15, quad = lane >> 4;                                 \
  const int ksw = (quad ^ (lr & 3)) * 8;                                      \
  const int offA0 = (wm * 128 + lr) * 32 + ksw;                               \
  const int offB0 = (wn * 64 + lr) * 32 + ksw;                                \
  f4_t acc[8][4];                                                             \
  _Pragma("unroll") for (int i_ = 0; i_ < 8; i_++)                            \
    _Pragma("unroll") for (int j_ = 0; j_ < 4; j_++)                          \
      acc[i_][j_] = (f4_t){0.f, 0.f, 0.f, 0.f};

#define G_ITER(SA_STAGE, SB_STAGE, TAILV) do {                                \
    const __bf16* aBp = sA + cur * 8192;                                      \
    const __bf16* bBp = sB + cur * 8192;                                      \
    bf8_t a0, a1, a2, a3, b0, b1, b2, b3;                                     \
    a0 = *(const bf8_t*)(aBp + offA0);                                        \
    a1 = *(const bf8_t*)(aBp + offA0 + 512);                                  \
    a2 = *(const bf8_t*)(aBp + offA0 + 1024);                                 \
    a3 = *(const bf8_t*)(aBp + offA0 + 1536);                                 \
    b0 = *(const bf8_t*)(bBp + offB0);                                        \
    b1 = *(const bf8_t*)(bBp + offB0 + 512);                                  \
    b2 = *(const bf8_t*)(bBp + offB0 + 1024);                                 \
    b3 = *(const bf8_t*)(bBp + offB0 + 1536);                                 \
    SA_STAGE;                                                                 \
    __builtin_amdgcn_s_barrier();                                             \
    __builtin_amdgcn_s_setprio(1);                                            \
    MFMA16(a0, b0, acc[0][0]); MFMA16(a0, b1, acc[0][1]);                     \
    MFMA16(a0, b2, acc[0][2]); MFMA16(a0, b3, acc[0][3]);                     \
    MFMA16(a1, b0, acc[1][0]); MFMA16(a1, b1, acc[1][1]);                     \
    MFMA16(a1, b2, acc[1][2]); MFMA16(a1, b3, acc[1][3]);                     \
    MFMA16(a2, b0, acc[2][0]); MFMA16(a2, b1, acc[2][1]);                     \
    MFMA16(a2, b2, acc[2][2]); MFMA16(a2, b3, acc[2][3]);                     \
    MFMA16(a3, b0, acc[3][0]); MFMA16(a3, b1, acc[3][1]);                     \
    MFMA16(a3, b2, acc[3][2]); MFMA16(a3, b3, acc[3][3]);                     \
    __builtin_amdgcn_s_setprio(0);                                            \
    __builtin_amdgcn_s_barrier();                                             \
    a0 = *(const bf8_t*)(aBp + offA0 + 2048);                                 \
    a1 = *(const bf8_t*)(aBp + offA0 + 2560);                                 \
    a2 = *(const bf8_t*)(aBp + offA0 + 3072);                                 \
    a3 = *(const bf8_t*)(aBp + offA0 + 3584);                                 \
    SB_STAGE;                                                                 \
    __builtin_amdgcn_s_barrier();                                             \
    __builtin_amdgcn_s_setprio(1);                                            \
    MFMA16(a0, b0, acc[4][0]); MFMA16(a0, b1, acc[4][1]);                     \
    MFMA16(a0, b2, acc[4][2]); MFMA16(a0, b3, acc[4][3]);                     \
    MFMA16(a1, b0, acc[5][0]); MFMA16(a1, b1, acc[5][1]);                     \
    MFMA16(a1, b2, acc[5][2]); MFMA16(a1, b3, acc[5][3]);                     \
    MFMA16(a2, b0, acc[6][0]); MFMA16(a2, b1, acc[6][1]);                     \
    MFMA16(a2, b2, acc[6][2]); MFMA16(a2, b3, acc[6][3]);                     \
    MFMA16(a3, b0, acc[7][0]); MFMA16(a3, b1, acc[7][1]);                     \
    MFMA16(a3, b2, acc[7][2]); MFMA16(a3, b3, acc[7][3]);                     \
    __builtin_amdgcn_s_setprio(0);                                            \
    TAILV;                                                                    \
    __builtin_amdgcn_s_barrier();                                             \
  } while (0)

// K = 768 = 24 tiles of BK=32.  Main loop t=0..21 (stages t+2, vmcnt(4));
// tail t=22 (no stage, vmcnt(0) waits tile 23); tail t=23 (pure compute).
#define G_MAIN() do {                                                         \
    STAGE_T(0, 0); STAGE_T(1, 32);                                            \
    asm volatile("s_waitcnt vmcnt(4)" ::: "memory");                          \
    __builtin_amdgcn_s_barrier();                                             \
    int cur = 0;                                                              \
    for (int t = 0; t < 22; t++) {                                            \
      int nx = cur + 2; if (nx > 2) nx -= 3;                                  \
      const int kc = t * 32 + 64;                                             \
      G_ITER({ SAu(nx, 0, kc); SAu(nx, 1, kc); },                             \
             { SBu(nx, 0, kc); SBu(nx, 1, kc); },                             \
             { asm volatile("s_waitcnt vmcnt(4)" ::: "memory"); });           \
      cur++; if (cur > 2) cur = 0;                                            \
    }                                                                         \
    G_ITER({}, {}, { asm volatile("s_waitcnt vmcnt(0)" ::: "memory"); });     \
    cur++; if (cur > 2) cur = 0;                                              \
    G_ITER({}, {}, {});                                                       \
  } while (0)

// ---------------- K1: GEMM1 kv = Xb @ Wqkv[:,768:] --------------------------
// A [32768,768] bf16 RM, B^T = WqkvT rows 768..2303 [1536,768] bf16 RM.
// grid 768 = 128 mt x 6 nt; XCD swizzle: 16 mt per XCD (A-tile L2 reuse,
// B 2.25 MB L2-resident).
__global__ __launch_bounds__(512, 2) void gemm1_kv(const __bf16* __restrict__ A,
                                                   const __bf16* __restrict__ B,
                                                   __bf16* __restrict__ KTo,
                                                   __bf16* __restrict__ VTo) {
  __shared__ __bf16 sA[3 * 8192];   // 3 x [256][32], 48 KiB
  __shared__ __bf16 sB[3 * 8192];   // 3 x [256][32], 48 KiB
  const int xcd = blockIdx.x & 7, g = blockIdx.x >> 3;
  const int mt = xcd * 16 + g / 6, nt = g % 6;
  G_SETUP();
  const __bf16* gA = A + (size_t)(mt * 256 + srow) * 768 + gcol;
  const __bf16* gB = B + (size_t)(nt * 256 + srow) * 768 + gcol;

  G_MAIN();

  // epilogue: C row = token, col in [0,1536): nt<3 -> K, nt>=3 -> V.
  // C/D frag layout: col = lane&15, row = quad*4 + reg.
  const int sKV = (nt >= 3);
  __bf16* T = sKV ? VTo : KTo;
  const int cw = (nt - sKV * 3) * 256 + wn * 64;   // 0..767 within K or V
  const int b = mt >> 4;                            // 16 m-tiles per batch
  const int n0 = (mt & 15) * 256 + wm * 128 + quad * 4;
#pragma unroll
  for (int ci = 0; ci < 4; ci++) {
    int cc = cw + ci * 16;
    __bf16* Tp = T + ((size_t)(b * 12 + (cc >> 6)) * 64 + (cc & 63) + lr) * 4096;
#pragma unroll
    for (int ri = 0; ri < 8; ri++) {
      union { __bf16 h4[4]; uint2 u2; } pk;
#pragma unroll
      for (int r = 0; r < 4; r++) pk.h4[r] = (__bf16)acc[ri][ci][r];
      *(uint2*)&Tp[n0 + ri * 16] = pk.u2;
    }
  }
}

// ------ K3: row stats (max, 1/sumexp) per KT row; NO writeback --------------
__global__ __launch_bounds__(256) void stats_rows(const __bf16* __restrict__ KT,
                                                  float2* __restrict__ stats) {
  __shared__ float red[8];
  const __bf16* p = KT + (size_t)blockIdx.x * 4096;
  const int tid = threadIdx.x, lane = tid & 63, wv = tid >> 6;
  bf8_t x0 = *(const bf8_t*)&p[tid * 16];
  bf8_t x1 = *(const bf8_t*)&p[tid * 16 + 8];
  float v[16];
#pragma unroll
  for (int k = 0; k < 8; k++) { v[k] = (float)x0[k]; v[8 + k] = (float)x1[k]; }
  float m = v[0];
#pragma unroll
  for (int k = 1; k < 16; k++) m = fmaxf(m, v[k]);
  for (int o = 32; o; o >>= 1) m = fmaxf(m, __shfl_xor(m, o, 64));
  if (lane == 0) red[wv] = m;
  __syncthreads();
  m = fmaxf(fmaxf(red[0], red[1]), fmaxf(red[2], red[3]));
  float s = 0.f;
#pragma unroll
  for (int k = 0; k < 16; k++) s += __expf(v[k] - m);
  for (int o = 32; o; o >>= 1) s += __shfl_xor(s, o, 64);
  if (lane == 0) red[4 + wv] = s;
  __syncthreads();
  if (tid == 0) {
    float st = red[4] + red[5] + red[6] + red[7];
    stats[blockIdx.x] = make_float2(m, 1.0f / st);
  }
}

// --------- K4: ctx partials with inline exp. grid = 96*8 --------------------
__global__ __launch_bounds__(256) void ctx_kernel(const __bf16* __restrict__ KT,
                                                  const __bf16* __restrict__ VT,
                                                  const float2* __restrict__ stats,
                                                  float* __restrict__ part) {
  const int bh = blockIdx.x >> 3, kc = blockIdx.x & 7;
  const int tid = threadIdx.x, lane = tid & 63, wv = tid >> 6;
  const int wr = (wv >> 1) * 32, wc = (wv & 1) * 32;
  const int lr = lane & 15, quad = lane >> 4;
  const __bf16* Ab = KT + (size_t)bh * 64 * 4096;
  const __bf16* Bb = VT + (size_t)bh * 64 * 4096;
  float2 st[2];
  st[0] = stats[bh * 64 + wr + lr];
  st[1] = stats[bh * 64 + wr + 16 + lr];
  const f4_t fz = {0.f, 0.f, 0.f, 0.f};
  f4_t acc[2][2] = {{fz, fz}, {fz, fz}};
  const int kbeg = kc * 512;
  for (int k0 = kbeg; k0 < kbeg + 512; k0 += 32) {
    bf8_t a[2], b[2];
#pragma unroll
    for (int i = 0; i < 2; i++) {
      bf8_t raw = *(const bf8_t*)&Ab[(size_t)(wr + i * 16 + lr) * 4096 + k0 + quad * 8];
#pragma unroll
      for (int e = 0; e < 8; e++)
        a[i][e] = (__bf16)(__expf((float)raw[e] - st[i].x) * st[i].y);
    }
#pragma unroll
    for (int j = 0; j < 2; j++)
      b[j] = *(const bf8_t*)&Bb[(size_t)(wc + j * 16 + lr) * 4096 + k0 + quad * 8];
#pragma unroll
    for (int i = 0; i < 2; i++)
#pragma unroll
      for (int j = 0; j < 2; j++)
        acc[i][j] = __builtin_amdgcn_mfma_f32_16x16x32_bf16(a[i], b[j], acc[i][j], 0, 0, 0);
  }
  float* po = part + (size_t)blockIdx.x * 4096;
#pragma unroll
  for (int i = 0; i < 2; i++)
#pragma unroll
    for (int j = 0; j < 2; j++)
#pragma unroll
      for (int r = 0; r < 4; r++)
        po[(wr + i * 16 + quad * 4 + r) * 64 + wc + j * 16 + lr] = acc[i][j][r];
}

// -------- K5: B2T[b][c][h*64+d] = sum_e ctx[bh][d][e] * Wproj[h*64+e][c] ----
__global__ __launch_bounds__(256) void wfused_kernel(const float* __restrict__ part,
                                                     const __bf16* __restrict__ WpT,
                                                     __bf16* __restrict__ B2T) {
  __shared__ __bf16 sctx[64 * 64];
  const int bh = blockIdx.x, cblk = blockIdx.y;
  const int b = bh / 12, h = bh % 12;
  const int tid = threadIdx.x;
  for (int i = tid; i < 4096; i += 256) {
    float s = 0.f;
#pragma unroll
    for (int kc = 0; kc < 8; kc++) s += part[(size_t)(bh * 8 + kc) * 4096 + i];
    sctx[i] = (__bf16)s;
  }
  __syncthreads();
  const int lane = tid & 63, wv = tid >> 6, lr = lane & 15, quad = lane >> 4;
  const int c0 = cblk * 192 + wv * 48;
  const f4_t fz = {0.f, 0.f, 0.f, 0.f};
  f4_t acc[3][4];
#pragma unroll
  for (int i = 0; i < 3; i++)
#pragma unroll
    for (int j = 0; j < 4; j++) acc[i][j] = fz;
#pragma unroll
  for (int k0 = 0; k0 < 64; k0 += 32) {
    bf8_t a[3], bq[4];
#pragma unroll
    for (int i = 0; i < 3; i++)
      a[i] = *(const bf8_t*)&WpT[(size_t)(c0 + i * 16 + lr) * 768 + h * 64 + k0 + quad * 8];
#pragma unroll
    for (int j = 0; j < 4; j++)
      bq[j] = *(const bf8_t*)&sctx[(j * 16 + lr) * 64 + k0 + quad * 8];
#pragma unroll
    for (int i = 0; i < 3; i++)
#pragma unroll
      for (int j = 0; j < 4; j++)
        acc[i][j] = __builtin_amdgcn_mfma_f32_16x16x32_bf16(a[i], bq[j], acc[i][j], 0, 0, 0);
  }
#pragma unroll
  for (int i = 0; i < 3; i++)
#pragma unroll
    for (int j = 0; j < 4; j++)
#pragma unroll
      for (int r = 0; r < 4; r++) {
        int c = c0 + i * 16 + quad * 4 + r;
        int d = j * 16 + lr;
        B2T[((size_t)b * 768 + c) * 768 + h * 64 + d] = (__bf16)acc[i][j][r];
      }
}

// ------ K5b: combine  Wcomb^T[b][c_out][c_in] = sum_k B2T[b][c_out][k]*Wq[c_in][k]
__global__ __launch_bounds__(256) void combine_kernel(const __bf16* __restrict__ B2Tall,
                                                      const __bf16* __restrict__ Wq,
                                                      __bf16* __restrict__ Wcomb) {
  constexpr int LD = 768, BK = 32, KTOT = 768;
  __shared__ __bf16 sAc[64 * 32];
  __shared__ __bf16 sBc[64 * 32];
  const int b = blockIdx.x / 144, rem = blockIdx.x % 144;
  const int mt = rem / 12, nt = rem % 12;
  const __bf16* A = B2Tall + (size_t)b * 768 * 768;
  const int tid = threadIdx.x, lane = tid & 63, wv = tid >> 6;
  const int wr = (wv >> 1) * 32, wc = (wv & 1) * 32;
  const int lr = lane & 15, quad = lane >> 4;

  const int e0 = tid * 8;
  const int srow = e0 >> 5, skk = e0 & 31;
  const __bf16* gA = A + (size_t)(mt * 64 + srow) * LD + skk;
  const __bf16* gB = Wq + (size_t)(nt * 64 + srow) * LD + skk;

  const f4_t fz = {0.f, 0.f, 0.f, 0.f};
  f4_t acc[2][2] = {{fz, fz}, {fz, fz}};

  for (int k0 = 0; k0 < KTOT; k0 += BK) {
    gload16(gA, &sAc[e0]);
    gload16(gB, &sBc[e0]);
    gA += BK; gB += BK;
    __syncthreads();
    bf8_t a[2], bq[2];
#pragma unroll
    for (int i = 0; i < 2; i++)
      a[i] = *(const bf8_t*)&sAc[(wr + i * 16 + lr) * 32 + quad * 8];
#pragma unroll
    for (int j = 0; j < 2; j++)
      bq[j] = *(const bf8_t*)&sBc[(wc + j * 16 + lr) * 32 + quad * 8];
#pragma unroll
    for (int i = 0; i < 2; i++)
#pragma unroll
      for (int j = 0; j < 2; j++)
        acc[i][j] = __builtin_amdgcn_mfma_f32_16x16x32_bf16(a[i], bq[j], acc[i][j], 0, 0, 0);
    __syncthreads();
  }
  __bf16* C = Wcomb + (size_t)b * 768 * 768;
  const int row0 = mt * 64 + wr, col0 = nt * 64 + wc;
#pragma unroll
  for (int i = 0; i < 2; i++)
#pragma unroll
    for (int j = 0; j < 2; j++)
#pragma unroll
      for (int r = 0; r < 4; r++)
        C[(size_t)(row0 + i * 16 + quad * 4 + r) * 768 + col0 + j * 16 + lr] =
            (__bf16)acc[i][j][r];
}

// ------------- K6: GEMM2 out = Xb @ Wcomb^T[b] + bproj ----------------------
// grid 384 = 128 mt x 3 nt; XCD swizzle: each XCD owns one batch -> Wcomb
// (1.2 MB) L2-resident.
__global__ __launch_bounds__(512, 2) void gemm2_out(const __bf16* __restrict__ A,
                                                    const __bf16* __restrict__ Ball,
                                                    float* __restrict__ C,
                                                    const float* __restrict__ bias) {
  __shared__ __bf16 sA[3 * 8192];
  __shared__ __bf16 sB[3 * 8192];
  const int xcd = blockIdx.x & 7, g = blockIdx.x >> 3;
  const int mt = xcd * 16 + g / 3, nt = g % 3;
  const __bf16* B = Ball + (size_t)(mt >> 4) * 768 * 768;
  G_SETUP();
  const __bf16* gA = A + (size_t)(mt * 256 + srow) * 768 + gcol;
  const __bf16* gB = B + (size_t)(nt * 256 + srow) * 768 + gcol;

  G_MAIN();

  const int row0 = mt * 256 + wm * 128 + quad * 4;
  const int col0 = nt * 256 + wn * 64;
#pragma unroll
  for (int ci = 0; ci < 4; ci++) {
    int col = col0 + ci * 16 + lr;
    float bv = bias[col];
#pragma unroll
    for (int ri = 0; ri < 8; ri++) {
#pragma unroll
      for (int r = 0; r < 4; r++)
        C[(size_t)(row0 + ri * 16 + r) * 768 + col] = acc[ri][ci][r] + bv;
    }
  }
}

// ---------------------------------------------------------------------------
extern "C" void kernel_launch(void* const* d_in, const int* in_sizes, int n_in,
                              void* d_out, int out_size, void* d_ws, size_t ws_size,
                              hipStream_t stream) {
  const float* x = (const float*)d_in[0];      // [8,4096,768]
  const float* Wqkv = (const float*)d_in[1];   // [768,2304]
  const float* Wproj = (const float*)d_in[2];  // [768,768]
  const float* bproj = (const float*)d_in[3];  // [768]
  float* out = (float*)d_out;                  // [8,4096,768]

  char* ws = (char*)d_ws;
  __bf16* Xb    = (__bf16*)(ws + 0);            // 50,331,648
  __bf16* KT    = (__bf16*)(ws + 50331648);     // 50,331,648
  __bf16* VT    = (__bf16*)(ws + 100663296);    // 50,331,648
  __bf16* WqkvT = (__bf16*)(ws + 150994944);    //  3,538,944 (dead after gemm1)
  float2* stats = (float2*)(ws + 150994944);    //  49,152 (aliases dead WqkvT)
  __bf16* Wqc   = (__bf16*)(ws + 154533888);    //  1,179,648
  __bf16* WpT   = (__bf16*)(ws + 155713536);    //  1,179,648
  float*  part  = (float*)(ws + 156893184);     // 12,582,912
  __bf16* B2T   = (__bf16*)(ws + 169476096);    //  9,437,184
  __bf16* Wcomb = (__bf16*)(ws + 178913280);    //  9,437,184 -> end 188,350,464

  cast_f32_bf16<<<24576, 256, 0, stream>>>(x, Xb, 25165824 / 4);
  transpose_cast<<<12 * 36, 256, 0, stream>>>(Wqkv, WqkvT, 768, 2304);
  wq_cast<<<(768 * 768) / 256, 256, 0, stream>>>(Wqkv, Wqc);
  transpose_cast<<<12 * 12, 256, 0, stream>>>(Wproj, WpT, 768, 768);
  gemm1_kv<<<768, 512, 0, stream>>>(Xb, WqkvT + 768 * 768, KT, VT);
  stats_rows<<<6144, 256, 0, stream>>>(KT, stats);
  ctx_kernel<<<96 * 8, 256, 0, stream>>>(KT, VT, stats, part);
  wfused_kernel<<<dim3(96, 4), 256, 0, stream>>>(part, WpT, B2T);
  combine_kernel<<<1152, 256, 0, stream>>>(B2T, Wqc, Wcomb);
  gemm2_out<<<384, 512, 0, stream>>>(Xb, Wcomb, out, bproj);
}

// Round 6
// 411.163 us; speedup vs baseline: 1.0668x; 1.0423x over previous
//
#include <hip/hip_runtime.h>
#include <cstdint>
#include <cstddef>

// ---------------------------------------------------------------------------
// EfficientAttention, Q-folded pipeline (Round 6, resubmit after broker
// timeout):
//   out = x @ (Wq @ Wfused[b]) + bias
// GEMM template: BM=BN=256, BK=64 (128B LDS rows, chunk^=row&7 swizzle — the
// only measured-0-conflict config), dbuf-2 (128 KiB), 8 waves 2Mx4N, per-wave
// 128x64 via 32x32x16 MFMA (4m x 2n x 4 kslices = 32 MFMA/tile, 24 ds_read
// /tile, each fragment read once).  4 barrier-paired phases per K-tile (m201
// shape); all 8 staging gloads issue in P1/P2 so the tile-end __syncthreads
// drain waits on ~2-phase-old loads (no just-issued drain stall).
// ---------------------------------------------------------------------------

typedef __bf16 bf8_t __attribute__((ext_vector_type(8)));
typedef float f4_t __attribute__((ext_vector_type(4)));
typedef float f16_t __attribute__((ext_vector_type(16)));

#define DEV_INLINE __device__ __forceinline__

DEV_INLINE void gload16(const void* g, void* l) {
  __builtin_amdgcn_global_load_lds(
      (const __attribute__((address_space(1))) void*)g,
      (__attribute__((address_space(3))) void*)l, 16, 0, 0);
}

// ---------------- K0a: cast x (fp32) -> bf16, 4 elems/thread ----------------
__global__ __launch_bounds__(256) void cast_f32_bf16(const float* __restrict__ in,
                                                     __bf16* __restrict__ out, int n4) {
  int i = blockIdx.x * 256 + threadIdx.x;
  if (i >= n4) return;
  float4 f = ((const float4*)in)[i];
  union { __bf16 h[4]; uint2 u; } o;
  o.h[0] = (__bf16)f.x; o.h[1] = (__bf16)f.y; o.h[2] = (__bf16)f.z; o.h[3] = (__bf16)f.w;
  ((uint2*)out)[i] = o.u;
}

// ---------- K0b: tiled transpose: out[c*R + r] = (bf16) in[r*C + c] ---------
__global__ __launch_bounds__(256) void transpose_cast(const float* __restrict__ in,
                                                      __bf16* __restrict__ out, int R, int C) {
  __shared__ float t[64][65];
  const int tilesR = R >> 6;
  const int tr = blockIdx.x % tilesR, tc = blockIdx.x / tilesR;
  const int tx = threadIdx.x & 63, ty = threadIdx.x >> 6;
  const int r0 = tr * 64, c0 = tc * 64;
#pragma unroll
  for (int p = 0; p < 16; p++) {
    int r = p * 4 + ty;
    t[r][tx] = in[(size_t)(r0 + r) * C + c0 + tx];
  }
  __syncthreads();
#pragma unroll
  for (int p = 0; p < 16; p++) {
    int c = p * 4 + ty;
    out[(size_t)(c0 + c) * R + r0 + tx] = (__bf16)t[tx][c];
  }
}

// ---- K0c: Wq_cast[r][k] = (bf16) Wqkv[r][k], k<768 (strided row cast) ------
__global__ __launch_bounds__(256) void wq_cast(const float* __restrict__ in,
                                               __bf16* __restrict__ out) {
  int o = blockIdx.x * 256 + threadIdx.x;   // o in [0, 768*768)
  int r = o / 768, c = o - r * 768;
  out[o] = (__bf16)in[r * 2304 + c];
}

// ---------------------------------------------------------------------------
// GEMM template macros.
//   LDS per matrix: 2 x [256 rows][64 bf16 = 128B].  Chunk c (16B) of row r
//   stored at slot c ^ (r&7); staging pre-swizzles the GLOBAL source column
//   (gload16 dest stays linear: buf + u*4096 + tid*8).
//   Fragment read (32x32x16): row = base + lane&31, k-chunk (2s|l5) ^ (r&7).
// ---------------------------------------------------------------------------

#define MFMA32(aa, bb, cc) cc = __builtin_amdgcn_mfma_f32_32x32x16_bf16(aa, bb, cc, 0, 0, 0)

#define SAu(d, u, kc) gload16(gA + (size_t)((u) * 64) * 768 + (kc),           \
                              sA + (d) * 16384 + (u) * 4096 + tid * 8)
#define SBu(d, u, kc) gload16(gB + (size_t)((u) * 64) * 768 + (kc),           \
                              sB + (d) * 16384 + (u) * 4096 + tid * 8)

#define G_SETUP()                                                             \
  const int tid = threadIdx.x;                                                \
  const int gcol = ((tid & 7) ^ ((tid >> 3) & 7)) * 8;                        \
  const int lane = tid & 63, wv = tid >> 6;                                   \
  const int wm = wv >> 2, wn = wv & 3;                                        \
  const int l31 = lane & 31, l5 = lane >> 5, key = lane & 7;                  \
  const int kof0 = ((0 | l5) ^ key) * 8;                                      \
  const int kof1 = ((2 | l5) ^ key) * 8;                                      \
  const int kof2 = ((4 | l5) ^ key) * 8;                                      \
  const int kof3 = ((6 | l5) ^ key) * 8;                                      \
  const int rowA = (wm * 128 + l31) * 64;                                     \
  const int rowB = (wn * 64 + l31) * 64;                                      \
  f16_t acc[4][2];                                                            \
  _Pragma("unroll") for (int i_ = 0; i_ < 4; i_++)                            \
    _Pragma("unroll") for (int j_ = 0; j_ < 2; j_++)                          \
      _Pragma("unroll") for (int e_ = 0; e_ < 16; e_++) acc[i_][j_][e_] = 0.f;

// One K-tile (BK=64): 4 phases; SA_STAGE issues in P1, SB_STAGE in P2;
// ends with __syncthreads() (drains the staged DMA + flips are done outside).
#define G_TILE(SA_STAGE, SB_STAGE) do {                                       \
    const __bf16* aBp = sA + cur * 16384;                                     \
    const __bf16* bBp = sB + cur * 16384;                                     \
    bf8_t a0x, a1x, a2x, a3x, a0y, a1y, a2y, a3y, bq0, bq1;                   \
    /* P1: A(s0,s1) + B(n0;s0,s1) */                                          \
    a0x = *(const bf8_t*)(aBp + rowA +        kof0);                          \
    a1x = *(const bf8_t*)(aBp + rowA + 2048 + kof0);                          \
    a2x = *(const bf8_t*)(aBp + rowA + 4096 + kof0);                          \
    a3x = *(const bf8_t*)(aBp + rowA + 6144 + kof0);                          \
    a0y = *(const bf8_t*)(aBp + rowA +        kof1);                          \
    a1y = *(const bf8_t*)(aBp + rowA + 2048 + kof1);                          \
    a2y = *(const bf8_t*)(aBp + rowA + 4096 + kof1);                          \
    a3y = *(const bf8_t*)(aBp + rowA + 6144 + kof1);                          \
    bq0 = *(const bf8_t*)(bBp + rowB + kof0);                                 \
    bq1 = *(const bf8_t*)(bBp + rowB + kof1);                                 \
    SA_STAGE;                                                                 \
    __builtin_amdgcn_s_barrier();                                             \
    __builtin_amdgcn_s_setprio(1);                                            \
    MFMA32(a0x, bq0, acc[0][0]); MFMA32(a0y, bq1, acc[0][0]);                 \
    MFMA32(a1x, bq0, acc[1][0]); MFMA32(a1y, bq1, acc[1][0]);                 \
    MFMA32(a2x, bq0, acc[2][0]); MFMA32(a2y, bq1, acc[2][0]);                 \
    MFMA32(a3x, bq0, acc[3][0]); MFMA32(a3y, bq1, acc[3][0]);                 \
    __builtin_amdgcn_s_setprio(0);                                            \
    __builtin_amdgcn_s_barrier();                                             \
    /* P2: B(n1;s0,s1), A held */                                             \
    bq0 = *(const bf8_t*)(bBp + rowB + 2048 + kof0);                          \
    bq1 = *(const bf8_t*)(bBp + rowB + 2048 + kof1);                          \
    SB_STAGE;                                                                 \
    __builtin_amdgcn_s_barrier();                                             \
    __builtin_amdgcn_s_setprio(1);                                            \
    MFMA32(a0x, bq0, acc[0][1]); MFMA32(a0y, bq1, acc[0][1]);                 \
    MFMA32(a1x, bq0, acc[1][1]); MFMA32(a1y, bq1, acc[1][1]);                 \
    MFMA32(a2x, bq0, acc[2][1]); MFMA32(a2y, bq1, acc[2][1]);                 \
    MFMA32(a3x, bq0, acc[3][1]); MFMA32(a3y, bq1, acc[3][1]);                 \
    __builtin_amdgcn_s_setprio(0);                                            \
    __builtin_amdgcn_s_barrier();                                             \
    /* P3: A(s2,s3) + B(n0;s2,s3) */                                          \
    a0x = *(const bf8_t*)(aBp + rowA +        kof2);                          \
    a1x = *(const bf8_t*)(aBp + rowA + 2048 + kof2);                          \
    a2x = *(const bf8_t*)(aBp + rowA + 4096 + kof2);                          \
    a3x = *(const bf8_t*)(aBp + rowA + 6144 + kof2);                          \
    a0y = *(const bf8_t*)(aBp + rowA +        kof3);                          \
    a1y = *(const bf8_t*)(aBp + rowA + 2048 + kof3);                          \
    a2y = *(const bf8_t*)(aBp + rowA + 4096 + kof3);                          \
    a3y = *(const bf8_t*)(aBp + rowA + 6144 + kof3);                          \
    bq0 = *(const bf8_t*)(bBp + rowB + kof2);                                 \
    bq1 = *(const bf8_t*)(bBp + rowB + kof3);                                 \
    __builtin_amdgcn_s_barrier();                                             \
    __builtin_amdgcn_s_setprio(1);                                            \
    MFMA32(a0x, bq0, acc[0][0]); MFMA32(a0y, bq1, acc[0][0]);                 \
    MFMA32(a1x, bq0, acc[1][0]); MFMA32(a1y, bq1, acc[1][0]);                 \
    MFMA32(a2x, bq0, acc[2][0]); MFMA32(a2y, bq1, acc[2][0]);                 \
    MFMA32(a3x, bq0, acc[3][0]); MFMA32(a3y, bq1, acc[3][0]);                 \
    __builtin_amdgcn_s_setprio(0);                                            \
    __builtin_amdgcn_s_barrier();                                             \
    /* P4: B(n1;s2,s3) */                                                     \
    bq0 = *(const bf8_t*)(bBp + rowB + 2048 + kof2);                          \
    bq1 = *(const bf8_t*)(bBp + rowB + 2048 + kof3);                          \
    __builtin_amdgcn_s_barrier();                                             \
    __builtin_amdgcn_s_setprio(1);                                            \
    MFMA32(a0x, bq0, acc[0][1]); MFMA32(a0y, bq1, acc[0][1]);                 \
    MFMA32(a1x, bq0, acc[1][1]); MFMA32(a1y, bq1, acc[1][1]);                 \
    MFMA32(a2x, bq0, acc[2][1]); MFMA32(a2y, bq1, acc[2][1]);                 \
    MFMA32(a3x, bq0, acc[3][1]); MFMA32(a3y, bq1, acc[3][1]);                 \
    __builtin_amdgcn_s_setprio(0);                                            \
    __syncthreads();  /* tile boundary: drains staged DMA (vmcnt 0) */        \
  } while (0)

// K = 768 = 12 tiles of BK=64; dbuf-2.
#define G_MAIN() do {                                                         \
    SAu(0, 0, 0); SAu(0, 1, 0); SAu(0, 2, 0); SAu(0, 3, 0);                   \
    SBu(0, 0, 0); SBu(0, 1, 0); SBu(0, 2, 0); SBu(0, 3, 0);                   \
    __syncthreads();                                                          \
    int cur = 0;                                                              \
    for (int t = 0; t < 11; ++t) {                                            \
      const int kcn = (t + 1) * 64;                                           \
      const int nx = cur ^ 1;                                                 \
      G_TILE({ SAu(nx, 0, kcn); SAu(nx, 1, kcn);                              \
               SAu(nx, 2, kcn); SAu(nx, 3, kcn); },                           \
             { SBu(nx, 0, kcn); SBu(nx, 1, kcn);                              \
               SBu(nx, 2, kcn); SBu(nx, 3, kcn); });                          \
      cur = nx;                                                               \
    }                                                                         \
    G_TILE({}, {});                                                           \
  } while (0)

// ---------------- K1: GEMM1 kv = Xb @ Wqkv[:,768:] --------------------------
// A [32768,768] bf16 RM, B^T = WqkvT rows 768..2303 [1536,768] bf16 RM.
// grid 768 = 128 mt x 6 nt; XCD swizzle: 16 mt per XCD (A-tile L2 reuse).
__global__ __launch_bounds__(512, 2) void gemm1_kv(const __bf16* __restrict__ A,
                                                   const __bf16* __restrict__ B,
                                                   __bf16* __restrict__ KTo,
                                                   __bf16* __restrict__ VTo) {
  __shared__ __bf16 sA[2 * 16384];   // 2 x [256][64], 64 KiB
  __shared__ __bf16 sB[2 * 16384];   // 2 x [256][64], 64 KiB
  const int xcd = blockIdx.x & 7, g = blockIdx.x >> 3;
  const int mt = xcd * 16 + g / 6, nt = g % 6;
  G_SETUP();
  const __bf16* gA = A + (size_t)(mt * 256 + (tid >> 3)) * 768 + gcol;
  const __bf16* gB = B + (size_t)(nt * 256 + (tid >> 3)) * 768 + gcol;

  G_MAIN();

  // epilogue: C row = token, col in [0,1536): nt<3 -> K, nt>=3 -> V.
  // 32x32 C/D layout: col = lane&31, row = (reg&3) + 8*(reg>>2) + 4*l5.
  const int sKV = (nt >= 3);
  __bf16* T = sKV ? VTo : KTo;
  const int bb = mt >> 4;                          // 16 m-tiles per batch
  const int tok0 = (mt & 15) * 256 + wm * 128 + 4 * l5;
  const int cbase = (nt - sKV * 3) * 256 + wn * 64;
#pragma unroll
  for (int m = 0; m < 4; m++) {
#pragma unroll
    for (int n = 0; n < 2; n++) {
      int c = cbase + n * 32 + l31;
      __bf16* Tp = T + ((size_t)(bb * 12 + (c >> 6)) * 64 + (c & 63)) * 4096;
      int tk = tok0 + m * 32;
#pragma unroll
      for (int q = 0; q < 4; q++) {
        union { __bf16 h4[4]; uint2 u2; } pk;
#pragma unroll
        for (int r = 0; r < 4; r++) pk.h4[r] = (__bf16)acc[m][n][q * 4 + r];
        *(uint2*)&Tp[tk + 8 * q] = pk.u2;
      }
    }
  }
}

// ------ K3: row stats (max, 1/sumexp) per KT row; NO writeback --------------
__global__ __launch_bounds__(256) void stats_rows(const __bf16* __restrict__ KT,
                                                  float2* __restrict__ stats) {
  __shared__ float red[8];
  const __bf16* p = KT + (size_t)blockIdx.x * 4096;
  const int tid = threadIdx.x, lane = tid & 63, wv = tid >> 6;
  bf8_t x0 = *(const bf8_t*)&p[tid * 16];
  bf8_t x1 = *(const bf8_t*)&p[tid * 16 + 8];
  float v[16];
#pragma unroll
  for (int k = 0; k < 8; k++) { v[k] = (float)x0[k]; v[8 + k] = (float)x1[k]; }
  float m = v[0];
#pragma unroll
  for (int k = 1; k < 16; k++) m = fmaxf(m, v[k]);
  for (int o = 32; o; o >>= 1) m = fmaxf(m, __shfl_xor(m, o, 64));
  if (lane == 0) red[wv] = m;
  __syncthreads();
  m = fmaxf(fmaxf(red[0], red[1]), fmaxf(red[2], red[3]));
  float s = 0.f;
#pragma unroll
  for (int k = 0; k < 16; k++) s += __expf(v[k] - m);
  for (int o = 32; o; o >>= 1) s += __shfl_xor(s, o, 64);
  if (lane == 0) red[4 + wv] = s;
  __syncthreads();
  if (tid == 0) {
    float st = red[4] + red[5] + red[6] + red[7];
    stats[blockIdx.x] = make_float2(m, 1.0f / st);
  }
}

// --------- K4: ctx partials with inline exp. grid = 96*8 --------------------
__global__ __launch_bounds__(256) void ctx_kernel(const __bf16* __restrict__ KT,
                                                  const __bf16* __restrict__ VT,
                                                  const float2* __restrict__ stats,
                                                  float* __restrict__ part) {
  const int bh = blockIdx.x >> 3, kc = blockIdx.x & 7;
  const int tid = threadIdx.x, lane = tid & 63, wv = tid >> 6;
  const int wr = (wv >> 1) * 32, wc = (wv & 1) * 32;
  const int lr = lane & 15, quad = lane >> 4;
  const __bf16* Ab = KT + (size_t)bh * 64 * 4096;
  const __bf16* Bb = VT + (size_t)bh * 64 * 4096;
  float2 st[2];
  st[0] = stats[bh * 64 + wr + lr];
  st[1] = stats[bh * 64 + wr + 16 + lr];
  const f4_t fz = {0.f, 0.f, 0.f, 0.f};
  f4_t acc[2][2] = {{fz, fz}, {fz, fz}};
  const int kbeg = kc * 512;
  for (int k0 = kbeg; k0 < kbeg + 512; k0 += 32) {
    bf8_t a[2], b[2];
#pragma unroll
    for (int i = 0; i < 2; i++) {
      bf8_t raw = *(const bf8_t*)&Ab[(size_t)(wr + i * 16 + lr) * 4096 + k0 + quad * 8];
#pragma unroll
      for (int e = 0; e < 8; e++)
        a[i][e] = (__bf16)(__expf((float)raw[e] - st[i].x) * st[i].y);
    }
#pragma unroll
    for (int j = 0; j < 2; j++)
      b[j] = *(const bf8_t*)&Bb[(size_t)(wc + j * 16 + lr) * 4096 + k0 + quad * 8];
#pragma unroll
    for (int i = 0; i < 2; i++)
#pragma unroll
      for (int j = 0; j < 2; j++)
        acc[i][j] = __builtin_amdgcn_mfma_f32_16x16x32_bf16(a[i], b[j], acc[i][j], 0, 0, 0);
  }
  float* po = part + (size_t)blockIdx.x * 4096;
#pragma unroll
  for (int i = 0; i < 2; i++)
#pragma unroll
    for (int j = 0; j < 2; j++)
#pragma unroll
      for (int r = 0; r < 4; r++)
        po[(wr + i * 16 + quad * 4 + r) * 64 + wc + j * 16 + lr] = acc[i][j][r];
}

// -------- K5: B2T[b][c][h*64+d] = sum_e ctx[bh][d][e] * Wproj[h*64+e][c] ----
__global__ __launch_bounds__(256) void wfused_kernel(const float* __restrict__ part,
                                                     const __bf16* __restrict__ WpT,
                                                     __bf16* __restrict__ B2T) {
  __shared__ __bf16 sctx[64 * 64];
  const int bh = blockIdx.x, cblk = blockIdx.y;
  const int b = bh / 12, h = bh % 12;
  const int tid = threadIdx.x;
  for (int i = tid; i < 4096; i += 256) {
    float s = 0.f;
#pragma unroll
    for (int kc = 0; kc < 8; kc++) s += part[(size_t)(bh * 8 + kc) * 4096 + i];
    sctx[i] = (__bf16)s;
  }
  __syncthreads();
  const int lane = tid & 63, wv = tid >> 6, lr = lane & 15, quad = lane >> 4;
  const int c0 = cblk * 192 + wv * 48;
  const f4_t fz = {0.f, 0.f, 0.f, 0.f};
  f4_t acc[3][4];
#pragma unroll
  for (int i = 0; i < 3; i++)
#pragma unroll
    for (int j = 0; j < 4; j++) acc[i][j] = fz;
#pragma unroll
  for (int k0 = 0; k0 < 64; k0 += 32) {
    bf8_t a[3], bq[4];
#pragma unroll
    for (int i = 0; i < 3; i++)
      a[i] = *(const bf8_t*)&WpT[(size_t)(c0 + i * 16 + lr) * 768 + h * 64 + k0 + quad * 8];
#pragma unroll
    for (int j = 0; j < 4; j++)
      bq[j] = *(const bf8_t*)&sctx[(j * 16 + lr) * 64 + k0 + quad * 8];
#pragma unroll
    for (int i = 0; i < 3; i++)
#pragma unroll
      for (int j = 0; j < 4; j++)
        acc[i][j] = __builtin_amdgcn_mfma_f32_16x16x32_bf16(a[i], bq[j], acc[i][j], 0, 0, 0);
  }
#pragma unroll
  for (int i = 0; i < 3; i++)
#pragma unroll
    for (int j = 0; j < 4; j++)
#pragma unroll
      for (int r = 0; r < 4; r++) {
        int c = c0 + i * 16 + quad * 4 + r;
        int d = j * 16 + lr;
        B2T[((size_t)b * 768 + c) * 768 + h * 64 + d] = (__bf16)acc[i][j][r];
      }
}

// ------ K5b: combine  Wcomb^T[b][c_out][c_in] = sum_k B2T[b][c_out][k]*Wq[c_in][k]
__global__ __launch_bounds__(256) void combine_kernel(const __bf16* __restrict__ B2Tall,
                                                      const __bf16* __restrict__ Wq,
                                                      __bf16* __restrict__ Wcomb) {
  constexpr int LD = 768, BK = 32, KTOT = 768;
  __shared__ __bf16 sAc[64 * 32];
  __shared__ __bf16 sBc[64 * 32];
  const int b = blockIdx.x / 144, rem = blockIdx.x % 144;
  const int mt = rem / 12, nt = rem % 12;
  const __bf16* A = B2Tall + (size_t)b * 768 * 768;
  const int tid = threadIdx.x, lane = tid & 63, wv = tid >> 6;
  const int wr = (wv >> 1) * 32, wc = (wv & 1) * 32;
  const int lr = lane & 15, quad = lane >> 4;

  const int e0 = tid * 8;
  const int srow = e0 >> 5, skk = e0 & 31;
  const __bf16* gA = A + (size_t)(mt * 64 + srow) * LD + skk;
  const __bf16* gB = Wq + (size_t)(nt * 64 + srow) * LD + skk;

  const f4_t fz = {0.f, 0.f, 0.f, 0.f};
  f4_t acc[2][2] = {{fz, fz}, {fz, fz}};

  for (int k0 = 0; k0 < KTOT; k0 += BK) {
    gload16(gA, &sAc[e0]);
    gload16(gB, &sBc[e0]);
    gA += BK; gB += BK;
    __syncthreads();
    bf8_t a[2], bq[2];
#pragma unroll
    for (int i = 0; i < 2; i++)
      a[i] = *(const bf8_t*)&sAc[(wr + i * 16 + lr) * 32 + quad * 8];
#pragma unroll
    for (int j = 0; j < 2; j++)
      bq[j] = *(const bf8_t*)&sBc[(wc + j * 16 + lr) * 32 + quad * 8];
#pragma unroll
    for (int i = 0; i < 2; i++)
#pragma unroll
      for (int j = 0; j < 2; j++)
        acc[i][j] = __builtin_amdgcn_mfma_f32_16x16x32_bf16(a[i], bq[j], acc[i][j], 0, 0, 0);
    __syncthreads();
  }
  __bf16* C = Wcomb + (size_t)b * 768 * 768;
  const int row0 = mt * 64 + wr, col0 = nt * 64 + wc;
#pragma unroll
  for (int i = 0; i < 2; i++)
#pragma unroll
    for (int j = 0; j < 2; j++)
#pragma unroll
      for (int r = 0; r < 4; r++)
        C[(size_t)(row0 + i * 16 + quad * 4 + r) * 768 + col0 + j * 16 + lr] =
            (__bf16)acc[i][j][r];
}

// ------------- K6: GEMM2 out = Xb @ Wcomb^T[b] + bproj ----------------------
// grid 384 = 128 mt x 3 nt; XCD swizzle: each XCD owns one batch -> Wcomb
// (1.2 MB) L2-resident.
__global__ __launch_bounds__(512, 2) void gemm2_out(const __bf16* __restrict__ A,
                                                    const __bf16* __restrict__ Ball,
                                                    float* __restrict__ C,
                                                    const float* __restrict__ bias) {
  __shared__ __bf16 sA[2 * 16384];
  __shared__ __bf16 sB[2 * 16384];
  const int xcd = blockIdx.x & 7, g = blockIdx.x >> 3;
  const int mt = xcd * 16 + g / 3, nt = g % 3;
  const __bf16* B = Ball + (size_t)(mt >> 4) * 768 * 768;
  G_SETUP();
  const __bf16* gA = A + (size_t)(mt * 256 + (tid >> 3)) * 768 + gcol;
  const __bf16* gB = B + (size_t)(nt * 256 + (tid >> 3)) * 768 + gcol;

  G_MAIN();

  const int row0 = mt * 256 + wm * 128 + 4 * l5;
  const int col0 = nt * 256 + wn * 64;
#pragma unroll
  for (int m = 0; m < 4; m++) {
#pragma unroll
    for (int n = 0; n < 2; n++) {
      int col = col0 + n * 32 + l31;
      float bv = bias[col];
#pragma unroll
      for (int q = 0; q < 4; q++) {
        int rb = row0 + m * 32 + 8 * q;
#pragma unroll
        for (int r = 0; r < 4; r++)
          C[(size_t)(rb + r) * 768 + col] = acc[m][n][q * 4 + r] + bv;
      }
    }
  }
}

// ---------------------------------------------------------------------------
extern "C" void kernel_launch(void* const* d_in, const int* in_sizes, int n_in,
                              void* d_out, int out_size, void* d_ws, size_t ws_size,
                              hipStream_t stream) {
  const float* x = (const float*)d_in[0];      // [8,4096,768]
  const float* Wqkv = (const float*)d_in[1];   // [768,2304]
  const float* Wproj = (const float*)d_in[2];  // [768,768]
  const float* bproj = (const float*)d_in[3];  // [768]
  float* out = (float*)d_out;                  // [8,4096,768]

  char* ws = (char*)d_ws;
  __bf16* Xb    = (__bf16*)(ws + 0);            // 50,331,648
  __bf16* KT    = (__bf16*)(ws + 50331648);     // 50,331,648
  __bf16* VT    = (__bf16*)(ws + 100663296);    // 50,331,648
  __bf16* WqkvT = (__bf16*)(ws + 150994944);    //  3,538,944 (dead after gemm1)
  float2* stats = (float2*)(ws + 150994944);    //  49,152 (aliases dead WqkvT)
  __bf16* Wqc   = (__bf16*)(ws + 154533888);    //  1,179,648
  __bf16* WpT   = (__bf16*)(ws + 155713536);    //  1,179,648
  float*  part  = (float*)(ws + 156893184);     // 12,582,912
  __bf16* B2T   = (__bf16*)(ws + 169476096);    //  9,437,184
  __bf16* Wcomb = (__bf16*)(ws + 178913280);    //  9,437,184 -> end 188,350,464

  cast_f32_bf16<<<24576, 256, 0, stream>>>(x, Xb, 25165824 / 4);
  transpose_cast<<<12 * 36, 256, 0, stream>>>(Wqkv, WqkvT, 768, 2304);
  wq_cast<<<(768 * 768) / 256, 256, 0, stream>>>(Wqkv, Wqc);
  transpose_cast<<<12 * 12, 256, 0, stream>>>(Wproj, WpT, 768, 768);
  gemm1_kv<<<768, 512, 0, stream>>>(Xb, WqkvT + 768 * 768, KT, VT);
  stats_rows<<<6144, 256, 0, stream>>>(KT, stats);
  ctx_kernel<<<96 * 8, 256, 0, stream>>>(KT, VT, stats, part);
  wfused_kernel<<<dim3(96, 4), 256, 0, stream>>>(part, WpT, B2T);
  combine_kernel<<<1152, 256, 0, stream>>>(B2T, Wqc, Wcomb);
  gemm2_out<<<384, 512, 0, stream>>>(Xb, Wcomb, out, bproj);
}

// Round 7
// 407.275 us; speedup vs baseline: 1.0770x; 1.0095x over previous
//
#include <hip/hip_runtime.h>
#include <cstdint>
#include <cstddef>

// ---------------------------------------------------------------------------
// EfficientAttention, Q-folded pipeline (Round 7):
//   out = x @ (Wq @ Wfused[b]) + bias
// GEMM template: BM=BN=256, BK=32 with the ONLY empirically-zero-conflict LDS
// geometry (round-2 bench): 64B rows, chunk ^= (row>>1)&3, 32-consecutive-row
// fragment reads, 32x32x16 MFMA.  Ring-4 LDS (128 KiB): compute tile t from
// buf t&3 while staging tile t+3 -> buf (t+3)&3; counted vmcnt(8) at tile end
// only (3-tile wait distance, m201 depth).  2 phases/tile x 8 MFMA, 2 gloads
// per phase, lgkmcnt(0) before each MFMA cluster, setprio(1) around clusters.
// ---------------------------------------------------------------------------

typedef __bf16 bf8_t __attribute__((ext_vector_type(8)));
typedef float f4_t __attribute__((ext_vector_type(4)));
typedef float f16_t __attribute__((ext_vector_type(16)));

#define DEV_INLINE __device__ __forceinline__

DEV_INLINE void gload16(const void* g, void* l) {
  __builtin_amdgcn_global_load_lds(
      (const __attribute__((address_space(1))) void*)g,
      (__attribute__((address_space(3))) void*)l, 16, 0, 0);
}

// ---------------- K0a: cast x (fp32) -> bf16, 4 elems/thread ----------------
__global__ __launch_bounds__(256) void cast_f32_bf16(const float* __restrict__ in,
                                                     __bf16* __restrict__ out, int n4) {
  int i = blockIdx.x * 256 + threadIdx.x;
  if (i >= n4) return;
  float4 f = ((const float4*)in)[i];
  union { __bf16 h[4]; uint2 u; } o;
  o.h[0] = (__bf16)f.x; o.h[1] = (__bf16)f.y; o.h[2] = (__bf16)f.z; o.h[3] = (__bf16)f.w;
  ((uint2*)out)[i] = o.u;
}

// ---------- K0b: tiled transpose: out[c*R + r] = (bf16) in[r*C + c] ---------
__global__ __launch_bounds__(256) void transpose_cast(const float* __restrict__ in,
                                                      __bf16* __restrict__ out, int R, int C) {
  __shared__ float t[64][65];
  const int tilesR = R >> 6;
  const int tr = blockIdx.x % tilesR, tc = blockIdx.x / tilesR;
  const int tx = threadIdx.x & 63, ty = threadIdx.x >> 6;
  const int r0 = tr * 64, c0 = tc * 64;
#pragma unroll
  for (int p = 0; p < 16; p++) {
    int r = p * 4 + ty;
    t[r][tx] = in[(size_t)(r0 + r) * C + c0 + tx];
  }
  __syncthreads();
#pragma unroll
  for (int p = 0; p < 16; p++) {
    int c = p * 4 + ty;
    out[(size_t)(c0 + c) * R + r0 + tx] = (__bf16)t[tx][c];
  }
}

// ---- K0c: Wq_cast[r][k] = (bf16) Wqkv[r][k], k<768 (strided row cast) ------
__global__ __launch_bounds__(256) void wq_cast(const float* __restrict__ in,
                                               __bf16* __restrict__ out) {
  int o = blockIdx.x * 256 + threadIdx.x;   // o in [0, 768*768)
  int r = o / 768, c = o - r * 768;
  out[o] = (__bf16)in[r * 2304 + c];
}

// ---------------------------------------------------------------------------
// GEMM template macros.
//   LDS per matrix: 4 ring bufs x [256 rows][32 bf16 = 64B] = 64 KiB (A+B =
//   128 KiB).  16B chunk c of row r stored at slot c ^ ((r>>1)&3); staging
//   pre-swizzles the GLOBAL column (gload16 LDS dest stays linear).
//   Fragment read (32x32x16, k-slice s): row = base + (lane&31),
//   chunk = ((2s)|l5) ^ ((row>>1)&3)  — round-2-bench measured 0 conflicts.
// ---------------------------------------------------------------------------

#define MFMA32(aa, bb, cc) cc = __builtin_amdgcn_mfma_f32_32x32x16_bf16(aa, bb, cc, 0, 0, 0)

#define SAu(d, u, kc) gload16(gA + (size_t)((u) * 128) * 768 + (kc),          \
                              sA + (d) * 8192 + (u) * 4096 + tid * 8)
#define SBu(d, u, kc) gload16(gB + (size_t)((u) * 128) * 768 + (kc),          \
                              sB + (d) * 8192 + (u) * 4096 + tid * 8)
#define STAGE_T(d, kc) do { SAu(d,0,kc); SAu(d,1,kc); SBu(d,0,kc); SBu(d,1,kc); } while (0)

#define G_SETUP()                                                             \
  const int tid = threadIdx.x;                                                \
  const int srow = tid >> 2;                                                  \
  const int gcol = ((tid & 3) ^ ((srow >> 1) & 3)) * 8;                       \
  const int lane = tid & 63, wv = tid >> 6;                                   \
  const int wm = wv >> 2, wn = wv & 3;                                        \
  const int l31 = lane & 31, l5 = lane >> 5;                                  \
  const int key = (l31 >> 1) & 3;                                             \
  const int kof0 = ((0 | l5) ^ key) * 8;   /* k-slice 0 */                    \
  const int kof1 = ((2 | l5) ^ key) * 8;   /* k-slice 1 */                    \
  const int rowA = (wm * 128 + l31) * 32;  /* frag m adds m*1024 */           \
  const int rowB = (wn * 64 + l31) * 32;   /* frag n adds n*1024 */           \
  f16_t acc[4][2];                                                            \
  _Pragma("unroll") for (int i_ = 0; i_ < 4; i_++)                            \
    _Pragma("unroll") for (int j_ = 0; j_ < 2; j_++)                          \
      _Pragma("unroll") for (int e_ = 0; e_ < 16; e_++) acc[i_][j_][e_] = 0.f;

// One K-tile (BK=32): 2 phases x 8 MFMA.
//   P1: read A frags (8) + B n0 (2), issue SA stage, barrier, MFMA n0 column.
//   P2: read B n1 (2), issue SB stage, barrier, MFMA n1 column.
//   TAILV = counted vmcnt at tile end (before final barrier).
#define G_TILE(SA_STAGE, SB_STAGE, TAILV) do {                                \
    const __bf16* aBp = sA + cur * 8192;                                      \
    const __bf16* bBp = sB + cur * 8192;                                      \
    bf8_t a00, a01, a10, a11, a20, a21, a30, a31, b0, b1;                     \
    a00 = *(const bf8_t*)(aBp + rowA +        kof0);                          \
    a01 = *(const bf8_t*)(aBp + rowA +        kof1);                          \
    a10 = *(const bf8_t*)(aBp + rowA + 1024 + kof0);                          \
    a11 = *(const bf8_t*)(aBp + rowA + 1024 + kof1);                          \
    a20 = *(const bf8_t*)(aBp + rowA + 2048 + kof0);                          \
    a21 = *(const bf8_t*)(aBp + rowA + 2048 + kof1);                          \
    a30 = *(const bf8_t*)(aBp + rowA + 3072 + kof0);                          \
    a31 = *(const bf8_t*)(aBp + rowA + 3072 + kof1);                          \
    b0  = *(const bf8_t*)(bBp + rowB + kof0);                                 \
    b1  = *(const bf8_t*)(bBp + rowB + kof1);                                 \
    SA_STAGE;                                                                 \
    __builtin_amdgcn_s_barrier();                                             \
    asm volatile("s_waitcnt lgkmcnt(0)" ::: "memory");                        \
    __builtin_amdgcn_s_setprio(1);                                            \
    MFMA32(a00, b0, acc[0][0]); MFMA32(a01, b1, acc[0][0]);                   \
    MFMA32(a10, b0, acc[1][0]); MFMA32(a11, b1, acc[1][0]);                   \
    MFMA32(a20, b0, acc[2][0]); MFMA32(a21, b1, acc[2][0]);                   \
    MFMA32(a30, b0, acc[3][0]); MFMA32(a31, b1, acc[3][0]);                   \
    __builtin_amdgcn_s_setprio(0);                                            \
    __builtin_amdgcn_s_barrier();                                             \
    b0 = *(const bf8_t*)(bBp + rowB + 1024 + kof0);                           \
    b1 = *(const bf8_t*)(bBp + rowB + 1024 + kof1);                           \
    SB_STAGE;                                                                 \
    __builtin_amdgcn_s_barrier();                                             \
    asm volatile("s_waitcnt lgkmcnt(0)" ::: "memory");                        \
    __builtin_amdgcn_s_setprio(1);                                            \
    MFMA32(a00, b0, acc[0][1]); MFMA32(a01, b1, acc[0][1]);                   \
    MFMA32(a10, b0, acc[1][1]); MFMA32(a11, b1, acc[1][1]);                   \
    MFMA32(a20, b0, acc[2][1]); MFMA32(a21, b1, acc[2][1]);                   \
    MFMA32(a30, b0, acc[3][1]); MFMA32(a31, b1, acc[3][1]);                   \
    __builtin_amdgcn_s_setprio(0);                                            \
    TAILV;                                                                    \
    __builtin_amdgcn_s_barrier();                                             \
  } while (0)

// K = 768 = 24 tiles of BK=32; ring-4.  Prologue stages tiles 0..2; main loop
// t=0..20 stages t+3 and waits vmcnt(8) (t+2,t+3 in flight -> t+1 landed);
// tails: t=21 vmcnt(4), t=22 vmcnt(0), t=23 pure compute.
#define G_MAIN() do {                                                         \
    STAGE_T(0, 0); STAGE_T(1, 32); STAGE_T(2, 64);                            \
    asm volatile("s_waitcnt vmcnt(8)" ::: "memory");                          \
    __builtin_amdgcn_s_barrier();                                             \
    int cur = 0;                                                              \
    for (int t = 0; t < 21; ++t) {                                            \
      const int nx = (cur + 3) & 3;                                           \
      const int kcn = (t + 3) * 32;                                           \
      G_TILE({ SAu(nx, 0, kcn); SAu(nx, 1, kcn); },                           \
             { SBu(nx, 0, kcn); SBu(nx, 1, kcn); },                           \
             { asm volatile("s_waitcnt vmcnt(8)" ::: "memory"); });           \
      cur = (cur + 1) & 3;                                                    \
    }                                                                         \
    G_TILE({}, {}, { asm volatile("s_waitcnt vmcnt(4)" ::: "memory"); });     \
    cur = (cur + 1) & 3;                                                      \
    G_TILE({}, {}, { asm volatile("s_waitcnt vmcnt(0)" ::: "memory"); });     \
    cur = (cur + 1) & 3;                                                      \
    G_TILE({}, {}, {});                                                       \
  } while (0)

// ---------------- K1: GEMM1 kv = Xb @ Wqkv[:,768:] --------------------------
// A [32768,768] bf16 RM, B^T = WqkvT rows 768..2303 [1536,768] bf16 RM.
// grid 768 = 128 mt x 6 nt; XCD swizzle: 16 mt per XCD (A-tile L2 reuse).
__global__ __launch_bounds__(512, 2) void gemm1_kv(const __bf16* __restrict__ A,
                                                   const __bf16* __restrict__ B,
                                                   __bf16* __restrict__ KTo,
                                                   __bf16* __restrict__ VTo) {
  __shared__ __bf16 sA[4 * 8192];   // 4 x [256][32], 64 KiB
  __shared__ __bf16 sB[4 * 8192];   // 4 x [256][32], 64 KiB
  const int xcd = blockIdx.x & 7, g = blockIdx.x >> 3;
  const int mt = xcd * 16 + g / 6, nt = g % 6;
  G_SETUP();
  const __bf16* gA = A + (size_t)(mt * 256 + srow) * 768 + gcol;
  const __bf16* gB = B + (size_t)(nt * 256 + srow) * 768 + gcol;

  G_MAIN();

  // epilogue (verbatim from round-6 PASSED kernel): C row = token,
  // col in [0,1536): nt<3 -> K, nt>=3 -> V.
  // 32x32 C/D layout: col = lane&31, row = (reg&3) + 8*(reg>>2) + 4*l5.
  const int sKV = (nt >= 3);
  __bf16* T = sKV ? VTo : KTo;
  const int bb = mt >> 4;                          // 16 m-tiles per batch
  const int tok0 = (mt & 15) * 256 + wm * 128 + 4 * l5;
  const int cbase = (nt - sKV * 3) * 256 + wn * 64;
#pragma unroll
  for (int m = 0; m < 4; m++) {
#pragma unroll
    for (int n = 0; n < 2; n++) {
      int c = cbase + n * 32 + l31;
      __bf16* Tp = T + ((size_t)(bb * 12 + (c >> 6)) * 64 + (c & 63)) * 4096;
      int tk = tok0 + m * 32;
#pragma unroll
      for (int q = 0; q < 4; q++) {
        union { __bf16 h4[4]; uint2 u2; } pk;
#pragma unroll
        for (int r = 0; r < 4; r++) pk.h4[r] = (__bf16)acc[m][n][q * 4 + r];
        *(uint2*)&Tp[tk + 8 * q] = pk.u2;
      }
    }
  }
}

// ------ K3: row stats (max, 1/sumexp) per KT row; NO writeback --------------
__global__ __launch_bounds__(256) void stats_rows(const __bf16* __restrict__ KT,
                                                  float2* __restrict__ stats) {
  __shared__ float red[8];
  const __bf16* p = KT + (size_t)blockIdx.x * 4096;
  const int tid = threadIdx.x, lane = tid & 63, wv = tid >> 6;
  bf8_t x0 = *(const bf8_t*)&p[tid * 16];
  bf8_t x1 = *(const bf8_t*)&p[tid * 16 + 8];
  float v[16];
#pragma unroll
  for (int k = 0; k < 8; k++) { v[k] = (float)x0[k]; v[8 + k] = (float)x1[k]; }
  float m = v[0];
#pragma unroll
  for (int k = 1; k < 16; k++) m = fmaxf(m, v[k]);
  for (int o = 32; o; o >>= 1) m = fmaxf(m, __shfl_xor(m, o, 64));
  if (lane == 0) red[wv] = m;
  __syncthreads();
  m = fmaxf(fmaxf(red[0], red[1]), fmaxf(red[2], red[3]));
  float s = 0.f;
#pragma unroll
  for (int k = 0; k < 16; k++) s += __expf(v[k] - m);
  for (int o = 32; o; o >>= 1) s += __shfl_xor(s, o, 64);
  if (lane == 0) red[4 + wv] = s;
  __syncthreads();
  if (tid == 0) {
    float st = red[4] + red[5] + red[6] + red[7];
    stats[blockIdx.x] = make_float2(m, 1.0f / st);
  }
}

// --------- K4: ctx partials with inline exp. grid = 96*8 --------------------
__global__ __launch_bounds__(256) void ctx_kernel(const __bf16* __restrict__ KT,
                                                  const __bf16* __restrict__ VT,
                                                  const float2* __restrict__ stats,
                                                  float* __restrict__ part) {
  const int bh = blockIdx.x >> 3, kc = blockIdx.x & 7;
  const int tid = threadIdx.x, lane = tid & 63, wv = tid >> 6;
  const int wr = (wv >> 1) * 32, wc = (wv & 1) * 32;
  const int lr = lane & 15, quad = lane >> 4;
  const __bf16* Ab = KT + (size_t)bh * 64 * 4096;
  const __bf16* Bb = VT + (size_t)bh * 64 * 4096;
  float2 st[2];
  st[0] = stats[bh * 64 + wr + lr];
  st[1] = stats[bh * 64 + wr + 16 + lr];
  const f4_t fz = {0.f, 0.f, 0.f, 0.f};
  f4_t acc[2][2] = {{fz, fz}, {fz, fz}};
  const int kbeg = kc * 512;
  for (int k0 = kbeg; k0 < kbeg + 512; k0 += 32) {
    bf8_t a[2], b[2];
#pragma unroll
    for (int i = 0; i < 2; i++) {
      bf8_t raw = *(const bf8_t*)&Ab[(size_t)(wr + i * 16 + lr) * 4096 + k0 + quad * 8];
#pragma unroll
      for (int e = 0; e < 8; e++)
        a[i][e] = (__bf16)(__expf((float)raw[e] - st[i].x) * st[i].y);
    }
#pragma unroll
    for (int j = 0; j < 2; j++)
      b[j] = *(const bf8_t*)&Bb[(size_t)(wc + j * 16 + lr) * 4096 + k0 + quad * 8];
#pragma unroll
    for (int i = 0; i < 2; i++)
#pragma unroll
      for (int j = 0; j < 2; j++)
        acc[i][j] = __builtin_amdgcn_mfma_f32_16x16x32_bf16(a[i], b[j], acc[i][j], 0, 0, 0);
  }
  float* po = part + (size_t)blockIdx.x * 4096;
#pragma unroll
  for (int i = 0; i < 2; i++)
#pragma unroll
    for (int j = 0; j < 2; j++)
#pragma unroll
      for (int r = 0; r < 4; r++)
        po[(wr + i * 16 + quad * 4 + r) * 64 + wc + j * 16 + lr] = acc[i][j][r];
}

// -------- K5: B2T[b][c][h*64+d] = sum_e ctx[bh][d][e] * Wproj[h*64+e][c] ----
__global__ __launch_bounds__(256) void wfused_kernel(const float* __restrict__ part,
                                                     const __bf16* __restrict__ WpT,
                                                     __bf16* __restrict__ B2T) {
  __shared__ __bf16 sctx[64 * 64];
  const int bh = blockIdx.x, cblk = blockIdx.y;
  const int b = bh / 12, h = bh % 12;
  const int tid = threadIdx.x;
  for (int i = tid; i < 4096; i += 256) {
    float s = 0.f;
#pragma unroll
    for (int kc = 0; kc < 8; kc++) s += part[(size_t)(bh * 8 + kc) * 4096 + i];
    sctx[i] = (__bf16)s;
  }
  __syncthreads();
  const int lane = tid & 63, wv = tid >> 6, lr = lane & 15, quad = lane >> 4;
  const int c0 = cblk * 192 + wv * 48;
  const f4_t fz = {0.f, 0.f, 0.f, 0.f};
  f4_t acc[3][4];
#pragma unroll
  for (int i = 0; i < 3; i++)
#pragma unroll
    for (int j = 0; j < 4; j++) acc[i][j] = fz;
#pragma unroll
  for (int k0 = 0; k0 < 64; k0 += 32) {
    bf8_t a[3], bq[4];
#pragma unroll
    for (int i = 0; i < 3; i++)
      a[i] = *(const bf8_t*)&WpT[(size_t)(c0 + i * 16 + lr) * 768 + h * 64 + k0 + quad * 8];
#pragma unroll
    for (int j = 0; j < 4; j++)
      bq[j] = *(const bf8_t*)&sctx[(j * 16 + lr) * 64 + k0 + quad * 8];
#pragma unroll
    for (int i = 0; i < 3; i++)
#pragma unroll
      for (int j = 0; j < 4; j++)
        acc[i][j] = __builtin_amdgcn_mfma_f32_16x16x32_bf16(a[i], bq[j], acc[i][j], 0, 0, 0);
  }
#pragma unroll
  for (int i = 0; i < 3; i++)
#pragma unroll
    for (int j = 0; j < 4; j++)
#pragma unroll
      for (int r = 0; r < 4; r++) {
        int c = c0 + i * 16 + quad * 4 + r;
        int d = j * 16 + lr;
        B2T[((size_t)b * 768 + c) * 768 + h * 64 + d] = (__bf16)acc[i][j][r];
      }
}

// ------ K5b: combine  Wcomb^T[b][c_out][c_in] = sum_k B2T[b][c_out][k]*Wq[c_in][k]
__global__ __launch_bounds__(256) void combine_kernel(const __bf16* __restrict__ B2Tall,
                                                      const __bf16* __restrict__ Wq,
                                                      __bf16* __restrict__ Wcomb) {
  constexpr int LD = 768, BK = 32, KTOT = 768;
  __shared__ __bf16 sAc[64 * 32];
  __shared__ __bf16 sBc[64 * 32];
  const int b = blockIdx.x / 144, rem = blockIdx.x % 144;
  const int mt = rem / 12, nt = rem % 12;
  const __bf16* A = B2Tall + (size_t)b * 768 * 768;
  const int tid = threadIdx.x, lane = tid & 63, wv = tid >> 6;
  const int wr = (wv >> 1) * 32, wc = (wv & 1) * 32;
  const int lr = lane & 15, quad = lane >> 4;

  const int e0 = tid * 8;
  const int srow = e0 >> 5, skk = e0 & 31;
  const __bf16* gA = A + (size_t)(mt * 64 + srow) * LD + skk;
  const __bf16* gB = Wq + (size_t)(nt * 64 + srow) * LD + skk;

  const f4_t fz = {0.f, 0.f, 0.f, 0.f};
  f4_t acc[2][2] = {{fz, fz}, {fz, fz}};

  for (int k0 = 0; k0 < KTOT; k0 += BK) {
    gload16(gA, &sAc[e0]);
    gload16(gB, &sBc[e0]);
    gA += BK; gB += BK;
    __syncthreads();
    bf8_t a[2], bq[2];
#pragma unroll
    for (int i = 0; i < 2; i++)
      a[i] = *(const bf8_t*)&sAc[(wr + i * 16 + lr) * 32 + quad * 8];
#pragma unroll
    for (int j = 0; j < 2; j++)
      bq[j] = *(const bf8_t*)&sBc[(wc + j * 16 + lr) * 32 + quad * 8];
#pragma unroll
    for (int i = 0; i < 2; i++)
#pragma unroll
      for (int j = 0; j < 2; j++)
        acc[i][j] = __builtin_amdgcn_mfma_f32_16x16x32_bf16(a[i], bq[j], acc[i][j], 0, 0, 0);
    __syncthreads();
  }
  __bf16* C = Wcomb + (size_t)b * 768 * 768;
  const int row0 = mt * 64 + wr, col0 = nt * 64 + wc;
#pragma unroll
  for (int i = 0; i < 2; i++)
#pragma unroll
    for (int j = 0; j < 2; j++)
#pragma unroll
      for (int r = 0; r < 4; r++)
        C[(size_t)(row0 + i * 16 + quad * 4 + r) * 768 + col0 + j * 16 + lr] =
            (__bf16)acc[i][j][r];
}

// ------------- K6: GEMM2 out = Xb @ Wcomb^T[b] + bproj ----------------------
// grid 384 = 128 mt x 3 nt; XCD swizzle: each XCD owns one batch -> Wcomb
// (1.2 MB) L2-resident.
__global__ __launch_bounds__(512, 2) void gemm2_out(const __bf16* __restrict__ A,
                                                    const __bf16* __restrict__ Ball,
                                                    float* __restrict__ C,
                                                    const float* __restrict__ bias) {
  __shared__ __bf16 sA[4 * 8192];
  __shared__ __bf16 sB[4 * 8192];
  const int xcd = blockIdx.x & 7, g = blockIdx.x >> 3;
  const int mt = xcd * 16 + g / 3, nt = g % 3;
  const __bf16* B = Ball + (size_t)(mt >> 4) * 768 * 768;
  G_SETUP();
  const __bf16* gA = A + (size_t)(mt * 256 + srow) * 768 + gcol;
  const __bf16* gB = B + (size_t)(nt * 256 + srow) * 768 + gcol;

  G_MAIN();

  const int row0 = mt * 256 + wm * 128 + 4 * l5;
  const int col0 = nt * 256 + wn * 64;
#pragma unroll
  for (int m = 0; m < 4; m++) {
#pragma unroll
    for (int n = 0; n < 2; n++) {
      int col = col0 + n * 32 + l31;
      float bv = bias[col];
#pragma unroll
      for (int q = 0; q < 4; q++) {
        int rb = row0 + m * 32 + 8 * q;
#pragma unroll
        for (int r = 0; r < 4; r++)
          C[(size_t)(rb + r) * 768 + col] = acc[m][n][q * 4 + r] + bv;
      }
    }
  }
}

// ---------------------------------------------------------------------------
extern "C" void kernel_launch(void* const* d_in, const int* in_sizes, int n_in,
                              void* d_out, int out_size, void* d_ws, size_t ws_size,
                              hipStream_t stream) {
  const float* x = (const float*)d_in[0];      // [8,4096,768]
  const float* Wqkv = (const float*)d_in[1];   // [768,2304]
  const float* Wproj = (const float*)d_in[2];  // [768,768]
  const float* bproj = (const float*)d_in[3];  // [768]
  float* out = (float*)d_out;                  // [8,4096,768]

  char* ws = (char*)d_ws;
  __bf16* Xb    = (__bf16*)(ws + 0);            // 50,331,648
  __bf16* KT    = (__bf16*)(ws + 50331648);     // 50,331,648
  __bf16* VT    = (__bf16*)(ws + 100663296);    // 50,331,648
  __bf16* WqkvT = (__bf16*)(ws + 150994944);    //  3,538,944 (dead after gemm1)
  float2* stats = (float2*)(ws + 150994944);    //  49,152 (aliases dead WqkvT)
  __bf16* Wqc   = (__bf16*)(ws + 154533888);    //  1,179,648
  __bf16* WpT   = (__bf16*)(ws + 155713536);    //  1,179,648
  float*  part  = (float*)(ws + 156893184);     // 12,582,912
  __bf16* B2T   = (__bf16*)(ws + 169476096);    //  9,437,184
  __bf16* Wcomb = (__bf16*)(ws + 178913280);    //  9,437,184 -> end 188,350,464

  cast_f32_bf16<<<24576, 256, 0, stream>>>(x, Xb, 25165824 / 4);
  transpose_cast<<<12 * 36, 256, 0, stream>>>(Wqkv, WqkvT, 768, 2304);
  wq_cast<<<(768 * 768) / 256, 256, 0, stream>>>(Wqkv, Wqc);
  transpose_cast<<<12 * 12, 256, 0, stream>>>(Wproj, WpT, 768, 768);
  gemm1_kv<<<768, 512, 0, stream>>>(Xb, WqkvT + 768 * 768, KT, VT);
  stats_rows<<<6144, 256, 0, stream>>>(KT, stats);
  ctx_kernel<<<96 * 8, 256, 0, stream>>>(KT, VT, stats, part);
  wfused_kernel<<<dim3(96, 4), 256, 0, stream>>>(part, WpT, B2T);
  combine_kernel<<<1152, 256, 0, stream>>>(B2T, Wqc, Wcomb);
  gemm2_out<<<384, 512, 0, stream>>>(Xb, Wcomb, out, bproj);
}